// Round 3
// baseline (464.490 us; speedup 1.0000x reference)
//
#include <hip/hip_runtime.h>
#include <math.h>

#define NBOX   4096
#define NTHR   1024
#define MAXDET 300
#define CAP    3968          // fallback path: boxes kept in LDS
#define NWORDS (NBOX / 32)
#define ROWW   64            // ull words per supmat row (4096 bits)
#define SWMAX  48            // staged column words in supmat kernel (LDS cap)

typedef unsigned long long ull;

__device__ __forceinline__ float clipf(float v, float hi) {
  return fminf(fmaxf(v, 0.0f), hi);
}

__device__ __forceinline__ float getimg(const int* img_i) {
  int iv = *img_i;
  return (iv > 0 && iv < (1 << 24)) ? (float)iv : __int_as_float(iv);
}

// =================== kernel A: build keys + hybrid bitonic sort ===================
// key = (ordered_float_bits(weighted_score) << 32) | (0xFFFFFFFF - idx); descending
// sort == argsort(-weighted, stable). Invalid (score<=0.3) have high32=0 -> tail.
struct SMA { ull skey[NBOX]; int vcount; };

__global__ __launch_bounds__(NTHR)
void sort_kernel(const float* __restrict__ scores,
                 const int*   __restrict__ labels,
                 const float* __restrict__ cls_w,
                 int* __restrict__ ws_sorted,
                 int* __restrict__ ws_V,
                 int N)
{
  __shared__ SMA sm;
  const int b   = blockIdx.x;
  const int tid = threadIdx.x;
  const float* sc = scores + (size_t)b * N;
  const int*   lb = labels + (size_t)b * N;

  if (tid == 0) sm.vcount = 0;
  for (int i = tid; i < NBOX; i += NTHR) {
    float s = sc[i];
    ull key = (ull)(0xFFFFFFFFu - (unsigned)i);
    if (s > 0.3f) {                       // SCORE_THRESHOLD, strict >
      float w = s * cls_w[lb[i]];
      unsigned ub = __float_as_uint(w);
      ub = (ub & 0x80000000u) ? ~ub : (ub | 0x80000000u);
      key |= ((ull)ub << 32);
    }
    sm.skey[i] = key;
  }
  __syncthreads();

  const int lane  = tid & 63;
  const int wbase = (tid >> 6) << 8;
  ull v0, v1, v2, v3;

  #define LOADV  { v0 = sm.skey[wbase      + lane]; v1 = sm.skey[wbase + 64 + lane]; \
                   v2 = sm.skey[wbase +128 + lane]; v3 = sm.skey[wbase +192 + lane]; }
  #define STOREV { sm.skey[wbase      + lane] = v0; sm.skey[wbase + 64 + lane] = v1; \
                   sm.skey[wbase +128 + lane] = v2; sm.skey[wbase +192 + lane] = v3; }
  #define CSWAP_REG(va, vb, eo) { int e_ = wbase + (eo) + lane;                      \
      if ((((e_) & k) == 0) ? ((va) < (vb)) : ((va) > (vb))) { ull t_ = (va); (va) = (vb); (vb) = t_; } }
  #define CSWAP_SHFL(vr, eo) { int e_ = wbase + (eo) + lane;                         \
      ull c_ = __shfl_xor((vr), j);                                                  \
      bool km_ = ((((e_) & k) == 0) == ((lane & j) == 0));                           \
      (vr) = km_ ? ((vr) > c_ ? (vr) : c_) : ((vr) < c_ ? (vr) : c_); }
  #define LOCALPHASES(jmax) {                                                        \
      for (int j = (jmax); j >= 1; j >>= 1) {                                        \
        if (j == 128)     { CSWAP_REG(v0, v2, 0);  CSWAP_REG(v1, v3, 64);  }         \
        else if (j == 64) { CSWAP_REG(v0, v1, 0);  CSWAP_REG(v2, v3, 128); }         \
        else { CSWAP_SHFL(v0, 0); CSWAP_SHFL(v1, 64); CSWAP_SHFL(v2, 128); CSWAP_SHFL(v3, 192); } } }

  LOADV;
  for (int k = 2; k <= 256; k <<= 1) { LOCALPHASES(k >> 1); }
  STOREV;
  __syncthreads();

  for (int k = 512; k <= NBOX; k <<= 1) {
    for (int j = k >> 1; j >= 256; j >>= 1) {
      for (int i = tid; i < NBOX; i += NTHR) {
        int l = i ^ j;
        if (l > i) {
          ull a = sm.skey[i], c = sm.skey[l];
          if (((i & k) == 0) ? (a < c) : (a > c)) { sm.skey[i] = c; sm.skey[l] = a; }
        }
      }
      __syncthreads();
    }
    LOADV;
    LOCALPHASES(128);
    STOREV;
    __syncthreads();
  }

  int* wsb = ws_sorted + (size_t)b * N;
  wsb[wbase       + lane] = (int)(0xFFFFFFFFu - (unsigned)v0);
  wsb[wbase +  64 + lane] = (int)(0xFFFFFFFFu - (unsigned)v1);
  wsb[wbase + 128 + lane] = (int)(0xFFFFFFFFu - (unsigned)v2);
  wsb[wbase + 192 + lane] = (int)(0xFFFFFFFFu - (unsigned)v3);
  int vc = (int)((v0 >> 32) != 0) + (int)((v1 >> 32) != 0)
         + (int)((v2 >> 32) != 0) + (int)((v3 >> 32) != 0);
  atomicAdd(&sm.vcount, vc);
  __syncthreads();
  if (tid == 0) ws_V[b] = sm.vcount;
}

// =================== kernel P: gather sorted clipped+offset boxes + areas ===================
__global__ __launch_bounds__(NTHR)
void prep_kernel(const float* __restrict__ boxes,
                 const int*   __restrict__ labels,
                 const int*   __restrict__ img_i,
                 const int*   __restrict__ ws_sorted,
                 float4* __restrict__ obox,
                 float*  __restrict__ area,
                 int N)
{
  const int b = blockIdx.y;
  const int i = blockIdx.x * NTHR + threadIdx.x;
  float fimg = getimg(img_i);
  float offs = fimg + 1.0f;
  int orig = ws_sorted[(size_t)b * N + i];
  float4 bb = ((const float4*)(boxes + (size_t)b * N * 4))[orig];
  float off = (float)labels[(size_t)b * N + orig] * offs;
  bb.x = clipf(bb.x, fimg) + off;
  bb.y = clipf(bb.y, fimg) + off;
  bb.z = clipf(bb.z, fimg) + off;
  bb.w = clipf(bb.w, fimg) + off;
  obox[(size_t)b * NBOX + i] = bb;
  area[(size_t)b * NBOX + i] = fmaxf(bb.z - bb.x, 0.0f) * fmaxf(bb.w - bb.y, 0.0f);
}

// =================== kernel M: suppression-matrix (whole-GPU parallel) ===================
// supmat row i, word w: bit (j&63) set iff IoU(i, j) > th && j > i, j = w*64+(j&63)
__global__ __launch_bounds__(256)
void supmat_kernel(const float4* __restrict__ obox,
                   const float*  __restrict__ area,
                   const float*  __restrict__ nms_th,
                   const int*    __restrict__ ws_V,
                   ull* __restrict__ supmat)
{
  __shared__ float4 cbox[SWMAX * 64];
  __shared__ float  carea[SWMAX * 64];

  const int rt  = blockIdx.x;          // row tile (64 rows)
  const int b   = blockIdx.y;
  const int tid = threadIdx.x;
  const int V   = ws_V[b];
  const int JW  = (V + 63) >> 6;
  if (rt >= JW) return;

  double xt = (double)(*nms_th);
  float  th = (float)(1.0 / (1.0 + exp(-xt)));

  const int jw0 = rt;
  const int nw  = JW - jw0;
  const int sw  = (nw < SWMAX) ? nw : SWMAX;

  const float4* ob = obox + (size_t)b * NBOX;
  const float*  ar = area + (size_t)b * NBOX;
  for (int e = tid; e < sw * 64; e += 256) {
    cbox[e]  = ob[jw0 * 64 + e];
    carea[e] = ar[jw0 * 64 + e];
  }
  __syncthreads();

  const int wave = tid >> 6;
  const int lane = tid & 63;
  for (int rr = 0; rr < 16; ++rr) {
    const int i = rt * 64 + wave * 16 + rr;
    if (i >= V) continue;              // rows >= V never read by resolve
    const float4 bi = cbox[i - jw0 * 64];
    const float  ai = carea[i - jw0 * 64];
    ull* rowp = supmat + ((size_t)b * NBOX + i) * ROWW;
    for (int w = 0; w < nw; ++w) {
      const int jw = jw0 + w;
      const int j  = jw * 64 + lane;
      float4 bj; float aj;
      if (w < sw) { bj = cbox[w * 64 + lane];  aj = carea[w * 64 + lane]; }
      else        { bj = ob[j];                aj = ar[j]; }
      float xx1 = fmaxf(bi.x, bj.x);
      float yy1 = fmaxf(bi.y, bj.y);
      float xx2 = fminf(bi.z, bj.z);
      float yy2 = fminf(bi.w, bj.w);
      float inter = fmaxf(xx2 - xx1, 0.0f) * fmaxf(yy2 - yy1, 0.0f);
      float denom = ai + aj;           // ((areas[i] + areas[j]) - inter) + 1e-9, ref order
      denom = denom - inter;
      denom = denom + 1e-9f;
      float iou = inter / denom;
      ull word = __ballot((iou > th) && (j > i));
      if (lane == 0) rowp[jw] = word;
    }
  }
}

// =================== kernel R: greedy resolve (bit ops) + output ===================
__global__ __launch_bounds__(256)
void resolve_kernel(const float* __restrict__ boxes,
                    const float* __restrict__ scores,
                    const int*   __restrict__ labels,
                    const int*   __restrict__ img_i,
                    float* __restrict__ out,
                    int B, int N,
                    const int* __restrict__ ws_sorted,
                    const int* __restrict__ ws_V,
                    const ull* __restrict__ supmat)
{
  __shared__ int kept_pos[MAXDET];
  __shared__ int Ksh;

  const int b   = blockIdx.x;
  const int tid = threadIdx.x;
  const int V   = ws_V[b];
  const ull* smat = supmat + (size_t)b * NBOX * ROWW;

  if (tid < 64) {
    const int lane = tid;
    // distributed alive bitmap: lane w owns bits [w*64, w*64+64)
    ull alive = 0;
    {
      int lo = lane * 64;
      if (V > lo) { int n = V - lo; alive = (n >= 64) ? ~0ull : ((1ull << n) - 1ull); }
    }
    const int JW = (V + 63) >> 6;
    int total = 0;
    for (int t = 0; t < JW; ++t) {
      ull aw = __shfl(alive, t);       // this tile's 64 alive bits (uniform)
      if (!aw) continue;
      // lane l holds intra-tile suppressed-by mask of box t*64+l (diagonal word)
      ull supby = smat[(size_t)(t * 64 + lane) * ROWW + t];
      ull rem = aw;
      ull keptmask = 0;
      bool done = false;
      while (rem) {
        int l = __builtin_ctzll(rem);
        rem &= rem - 1;
        keptmask |= (1ull << l);
        if (lane == 0) kept_pos[total] = t * 64 + l;
        ++total;
        if (total == MAXDET) { done = true; break; }
        ull su = __shfl(supby, l);     // boxes suppressed by kept box l (j>l only)
        rem &= ~su;
      }
      if (done) break;
      // apply kept rows to future words (independent loads, then AND)
      ull acc = 0;
      ull km = keptmask;
      while (km) {
        int l = __builtin_ctzll(km);
        km &= km - 1;
        acc |= smat[(size_t)(t * 64 + l) * ROWW + lane];
      }
      if (lane > t) alive &= ~acc;     // words < t irrelevant; word t resolved
    }
    if (tid == 0) Ksh = total;
  }
  __syncthreads();
  const int K = Ksh;

  float fimg = getimg(img_i);
  const float* bx = boxes  + (size_t)b * N * 4;
  const float* sc = scores + (size_t)b * N;
  const int*   lb = labels + (size_t)b * N;
  const int*   so = ws_sorted + (size_t)b * N;

  float4* obx = (float4*)out;
  float*  osc = out + (size_t)B * MAXDET * 4;
  float*  olb = osc + (size_t)B * MAXDET;
  float*  ovl = olb + (size_t)B * MAXDET;
  for (int r = tid; r < MAXDET; r += 256) {
    size_t slot = (size_t)b * MAXDET + r;
    if (r < K) {
      int i    = kept_pos[r];
      int orig = so[i];
      float4 bb = ((const float4*)bx)[orig];
      bb.x = clipf(bb.x, fimg);
      bb.y = clipf(bb.y, fimg);
      bb.z = clipf(bb.z, fimg);
      bb.w = clipf(bb.w, fimg);
      obx[slot] = bb;
      osc[slot] = sc[orig];
      olb[slot] = (float)lb[orig];
      ovl[slot] = 1.0f;
    } else {
      obx[slot] = make_float4(0.f, 0.f, 0.f, 0.f);
      osc[slot] = 0.0f;
      olb[slot] = 0.0f;
      ovl[slot] = 0.0f;
    }
  }
}

// =================== fallback kernel (round-2, used if ws too small) ===================
struct SMB {
  float4       obox[CAP];
  unsigned int keepw[NWORDS];
  int          kept_pos[MAXDET];
  int          scal[4];
};

__global__ __launch_bounds__(NTHR)
void nms_kernel(const float* __restrict__ boxes,
                const float* __restrict__ scores,
                const int*   __restrict__ labels,
                const float* __restrict__ nms_th,
                const float* __restrict__ cls_w,
                const int*   __restrict__ img_i,
                float* __restrict__ out,
                int B, int N,
                const int* __restrict__ ws_sorted,
                const int* __restrict__ ws_V,
                float4* __restrict__ ws_ovf)
{
  __shared__ SMB sm;
  const int b    = blockIdx.x;
  const int tid  = threadIdx.x;

  const float* bx = boxes  + (size_t)b * N * 4;
  const float* sc = scores + (size_t)b * N;
  const int*   lb = labels + (size_t)b * N;
  const int*   so = ws_sorted + (size_t)b * N;

  float fimg = getimg(img_i);
  float off_scale = fimg + 1.0f;
  double xt = (double)(*nms_th);
  float  th = (float)(1.0 / (1.0 + exp(-xt)));

  const int V = ws_V[b];
  if (tid < 4) sm.scal[tid] = 0;

  for (int m = 0; m < 4; ++m) {
    int i = tid + m * NTHR;
    int orig = so[i];
    float4 bb = ((const float4*)bx)[orig];
    float off = (float)lb[orig] * off_scale;
    bb.x = clipf(bb.x, fimg) + off;
    bb.y = clipf(bb.y, fimg) + off;
    bb.z = clipf(bb.z, fimg) + off;
    bb.w = clipf(bb.w, fimg) + off;
    if (i < CAP) sm.obox[i] = bb;
    else         ws_ovf[(size_t)b * (NBOX - CAP) + (i - CAP)] = bb;
  }
  for (int w = tid; w < NWORDS; w += NTHR) {
    int lo = w * 32;
    unsigned val;
    if      (V >= lo + 32) val = 0xFFFFFFFFu;
    else if (V <= lo)      val = 0u;
    else                   val = (1u << (V - lo)) - 1u;
    sm.keepw[w] = val;
  }
  __syncthreads();

  const int nt = (V + 63) >> 6;
  int TR = 0;
  for (int t = 0; t < nt; ++t) {
    if (tid < 64) {
      int i0 = t * 64;
      int me = i0 + tid;
      float4 bb = (me < CAP) ? sm.obox[me]
                             : ws_ovf[(size_t)b * (NBOX - CAP) + (me - CAP)];
      float arJ = fmaxf(bb.z - bb.x, 0.0f) * fmaxf(bb.w - bb.y, 0.0f);
      ull supby = 0;
      for (int l = 0; l < 64; ++l) {
        int i = i0 + l;
        float4 bi = (i < CAP) ? sm.obox[i]
                              : ws_ovf[(size_t)b * (NBOX - CAP) + (i - CAP)];
        float ai = fmaxf(bi.z - bi.x, 0.0f) * fmaxf(bi.w - bi.y, 0.0f);
        float xx1 = fmaxf(bi.x, bb.x);
        float yy1 = fmaxf(bi.y, bb.y);
        float xx2 = fminf(bi.z, bb.z);
        float yy2 = fminf(bi.w, bb.w);
        float inter = fmaxf(xx2 - xx1, 0.0f) * fmaxf(yy2 - yy1, 0.0f);
        float denom = ai + arJ;
        denom = denom - inter;
        denom = denom + 1e-9f;
        float iou = inter / denom;
        if (iou > th) supby |= (1ull << l);
      }
      ull alive = ((ull)sm.keepw[2 * t + 1] << 32) | sm.keepw[2 * t];
      ull rem = alive;
      while (rem) {
        int l = __builtin_ctzll(rem);
        rem &= rem - 1;
        ull sup = __ballot((supby >> l) & 1ull);
        sup &= ((~1ull) << l);
        sup &= alive;
        alive &= ~sup;
        rem   &= ~sup;
      }
      if (tid == 0) {
        sm.keepw[2 * t]     = (unsigned)alive;
        sm.keepw[2 * t + 1] = (unsigned)(alive >> 32);
        atomicAdd(&sm.scal[1], __builtin_popcountll(alive));
      }
    }
    __syncthreads();
    TR = t + 1;
    if (sm.scal[1] >= MAXDET) break;

    int jstart = (t + 1) * 64;
    if (jstart < V) {
      ull alive = ((ull)sm.keepw[2 * t + 1] << 32) | sm.keepw[2 * t];
      if (alive) {
        for (int j = jstart + tid; j < V; j += NTHR) {
          unsigned wj = sm.keepw[j >> 5];
          if (!((wj >> (j & 31)) & 1u)) continue;
          float4 bj = (j < CAP) ? sm.obox[j]
                                : ws_ovf[(size_t)b * (NBOX - CAP) + (j - CAP)];
          float aj = fmaxf(bj.z - bj.x, 0.0f) * fmaxf(bj.w - bj.y, 0.0f);
          ull rem = alive;
          bool suppressed = false;
          while (rem) {
            int l = __builtin_ctzll(rem);
            rem &= rem - 1;
            int i = t * 64 + l;
            float4 bi = (i < CAP) ? sm.obox[i]
                                  : ws_ovf[(size_t)b * (NBOX - CAP) + (i - CAP)];
            float ai = fmaxf(bi.z - bi.x, 0.0f) * fmaxf(bi.w - bi.y, 0.0f);
            float xx1 = fmaxf(bi.x, bj.x);
            float yy1 = fmaxf(bi.y, bj.y);
            float xx2 = fminf(bi.z, bj.z);
            float yy2 = fminf(bi.w, bj.w);
            float inter = fmaxf(xx2 - xx1, 0.0f) * fmaxf(yy2 - yy1, 0.0f);
            float denom = ai + aj;
            denom = denom - inter;
            denom = denom + 1e-9f;
            float iou = inter / denom;
            if (iou > th) { suppressed = true; break; }
          }
          if (suppressed) atomicAnd(&sm.keepw[j >> 5], ~(1u << (j & 31)));
        }
      }
    }
    __syncthreads();
  }

  if (tid < NWORDS && tid >= TR * 2) sm.keepw[tid] = 0;
  __syncthreads();
  if (tid == 0) {
    int r = 0;
    for (int w = 0; w < NWORDS && r < MAXDET; ++w) {
      unsigned bits = sm.keepw[w];
      while (bits && r < MAXDET) {
        int l = __builtin_ctz(bits);
        bits &= bits - 1;
        sm.kept_pos[r++] = w * 32 + l;
      }
    }
    sm.scal[3] = r;
  }
  __syncthreads();
  const int K = sm.scal[3];

  float4* obx = (float4*)out;
  float*  osc = out + (size_t)B * MAXDET * 4;
  float*  olb = osc + (size_t)B * MAXDET;
  float*  ovl = olb + (size_t)B * MAXDET;
  for (int r = tid; r < MAXDET; r += NTHR) {
    size_t slot = (size_t)b * MAXDET + r;
    if (r < K) {
      int i    = sm.kept_pos[r];
      int orig = so[i];
      float4 bb = ((const float4*)bx)[orig];
      bb.x = clipf(bb.x, fimg);
      bb.y = clipf(bb.y, fimg);
      bb.z = clipf(bb.z, fimg);
      bb.w = clipf(bb.w, fimg);
      obx[slot] = bb;
      osc[slot] = sc[orig];
      olb[slot] = (float)lb[orig];
      ovl[slot] = 1.0f;
    } else {
      obx[slot] = make_float4(0.f, 0.f, 0.f, 0.f);
      osc[slot] = 0.0f;
      olb[slot] = 0.0f;
      ovl[slot] = 0.0f;
    }
  }
}

extern "C" void kernel_launch(void* const* d_in, const int* in_sizes, int n_in,
                              void* d_out, int out_size, void* d_ws, size_t ws_size,
                              hipStream_t stream) {
  const float* boxes      = (const float*)d_in[0];
  const float* scores     = (const float*)d_in[1];
  const int*   labels     = (const int*)d_in[2];
  const float* nms_thresh = (const float*)d_in[3];
  const float* cls_w      = (const float*)d_in[4];
  const int*   img_sz     = (const int*)d_in[5];

  int B = out_size / (MAXDET * 7);
  int N = in_sizes[1] / B;               // 4096

  // ws layout
  size_t sz_sorted = (size_t)B * N * 4;
  size_t off_V     = sz_sorted;
  size_t off_obox  = sz_sorted + 1024;
  size_t sz_obox   = (size_t)B * NBOX * 16;
  size_t off_area  = off_obox + sz_obox;
  size_t sz_area   = (size_t)B * NBOX * 4;
  size_t off_sup   = (off_area + sz_area + 255) & ~(size_t)255;
  size_t sz_sup    = (size_t)B * NBOX * ROWW * 8;   // 32 MiB at B=16
  size_t need_fast = off_sup + sz_sup;

  int*    ws_sorted = (int*)d_ws;
  int*    ws_V      = (int*)((char*)d_ws + off_V);

  sort_kernel<<<dim3(B), dim3(NTHR), 0, stream>>>(scores, labels, cls_w,
                                                  ws_sorted, ws_V, N);

  if (ws_size >= need_fast && N == NBOX) {
    float4* obox   = (float4*)((char*)d_ws + off_obox);
    float*  area   = (float*)((char*)d_ws + off_area);
    ull*    supmat = (ull*)((char*)d_ws + off_sup);

    prep_kernel<<<dim3(N / NTHR, B), dim3(NTHR), 0, stream>>>(
        boxes, labels, img_sz, ws_sorted, obox, area, N);
    supmat_kernel<<<dim3(NBOX / 64, B), dim3(256), 0, stream>>>(
        obox, area, nms_thresh, ws_V, supmat);
    resolve_kernel<<<dim3(B), dim3(256), 0, stream>>>(
        boxes, scores, labels, img_sz, (float*)d_out, B, N,
        ws_sorted, ws_V, supmat);
  } else {
    float4* ws_ovf = (float4*)((char*)d_ws + sz_sorted + 1024 + sz_obox + sz_area);
    nms_kernel<<<dim3(B), dim3(NTHR), 0, stream>>>(boxes, scores, labels,
                                                   nms_thresh, cls_w, img_sz,
                                                   (float*)d_out, B, N,
                                                   ws_sorted, ws_V, ws_ovf);
  }
}

// Round 4
// 291.374 us; speedup vs baseline: 1.5941x; 1.5941x over previous
//
#include <hip/hip_runtime.h>
#include <math.h>

#define NBOX   4096
#define NTHR   1024
#define MAXDET 300
#define CAP    3968          // fallback path: boxes kept in LDS
#define NWORDS (NBOX / 32)
#define ROWW   64            // ull words per supmat row (4096 bits)
#define CTW    16            // col-tile width in words (1024 boxes, 20KB LDS)

typedef unsigned long long ull;

__device__ __forceinline__ float clipf(float v, float hi) {
  return fminf(fmaxf(v, 0.0f), hi);
}

__device__ __forceinline__ float getimg(const int* img_i) {
  int iv = *img_i;
  return (iv > 0 && iv < (1 << 24)) ? (float)iv : __int_as_float(iv);
}

// =================== kernel A: build keys + hybrid bitonic sort ===================
struct SMA { ull skey[NBOX]; int vcount; };

__global__ __launch_bounds__(NTHR)
void sort_kernel(const float* __restrict__ scores,
                 const int*   __restrict__ labels,
                 const float* __restrict__ cls_w,
                 int* __restrict__ ws_sorted,
                 int* __restrict__ ws_V,
                 int N)
{
  __shared__ SMA sm;
  const int b   = blockIdx.x;
  const int tid = threadIdx.x;
  const float* sc = scores + (size_t)b * N;
  const int*   lb = labels + (size_t)b * N;

  if (tid == 0) sm.vcount = 0;
  for (int i = tid; i < NBOX; i += NTHR) {
    float s = sc[i];
    ull key = (ull)(0xFFFFFFFFu - (unsigned)i);
    if (s > 0.3f) {                       // SCORE_THRESHOLD, strict >
      float w = s * cls_w[lb[i]];
      unsigned ub = __float_as_uint(w);
      ub = (ub & 0x80000000u) ? ~ub : (ub | 0x80000000u);
      key |= ((ull)ub << 32);
    }
    sm.skey[i] = key;
  }
  __syncthreads();

  const int lane  = tid & 63;
  const int wbase = (tid >> 6) << 8;
  ull v0, v1, v2, v3;

  #define LOADV  { v0 = sm.skey[wbase      + lane]; v1 = sm.skey[wbase + 64 + lane]; \
                   v2 = sm.skey[wbase +128 + lane]; v3 = sm.skey[wbase +192 + lane]; }
  #define STOREV { sm.skey[wbase      + lane] = v0; sm.skey[wbase + 64 + lane] = v1; \
                   sm.skey[wbase +128 + lane] = v2; sm.skey[wbase +192 + lane] = v3; }
  #define CSWAP_REG(va, vb, eo) { int e_ = wbase + (eo) + lane;                      \
      if ((((e_) & k) == 0) ? ((va) < (vb)) : ((va) > (vb))) { ull t_ = (va); (va) = (vb); (vb) = t_; } }
  #define CSWAP_SHFL(vr, eo) { int e_ = wbase + (eo) + lane;                         \
      ull c_ = __shfl_xor((vr), j);                                                  \
      bool km_ = ((((e_) & k) == 0) == ((lane & j) == 0));                           \
      (vr) = km_ ? ((vr) > c_ ? (vr) : c_) : ((vr) < c_ ? (vr) : c_); }
  #define LOCALPHASES(jmax) {                                                        \
      for (int j = (jmax); j >= 1; j >>= 1) {                                        \
        if (j == 128)     { CSWAP_REG(v0, v2, 0);  CSWAP_REG(v1, v3, 64);  }         \
        else if (j == 64) { CSWAP_REG(v0, v1, 0);  CSWAP_REG(v2, v3, 128); }         \
        else { CSWAP_SHFL(v0, 0); CSWAP_SHFL(v1, 64); CSWAP_SHFL(v2, 128); CSWAP_SHFL(v3, 192); } } }

  LOADV;
  for (int k = 2; k <= 256; k <<= 1) { LOCALPHASES(k >> 1); }
  STOREV;
  __syncthreads();

  for (int k = 512; k <= NBOX; k <<= 1) {
    for (int j = k >> 1; j >= 256; j >>= 1) {
      for (int i = tid; i < NBOX; i += NTHR) {
        int l = i ^ j;
        if (l > i) {
          ull a = sm.skey[i], c = sm.skey[l];
          if (((i & k) == 0) ? (a < c) : (a > c)) { sm.skey[i] = c; sm.skey[l] = a; }
        }
      }
      __syncthreads();
    }
    LOADV;
    LOCALPHASES(128);
    STOREV;
    __syncthreads();
  }

  int* wsb = ws_sorted + (size_t)b * N;
  wsb[wbase       + lane] = (int)(0xFFFFFFFFu - (unsigned)v0);
  wsb[wbase +  64 + lane] = (int)(0xFFFFFFFFu - (unsigned)v1);
  wsb[wbase + 128 + lane] = (int)(0xFFFFFFFFu - (unsigned)v2);
  wsb[wbase + 192 + lane] = (int)(0xFFFFFFFFu - (unsigned)v3);
  int vc = (int)((v0 >> 32) != 0) + (int)((v1 >> 32) != 0)
         + (int)((v2 >> 32) != 0) + (int)((v3 >> 32) != 0);
  atomicAdd(&sm.vcount, vc);
  __syncthreads();
  if (tid == 0) ws_V[b] = sm.vcount;
}

// =================== kernel P: gather sorted clipped+offset boxes + areas ===================
__global__ __launch_bounds__(NTHR)
void prep_kernel(const float* __restrict__ boxes,
                 const int*   __restrict__ labels,
                 const int*   __restrict__ img_i,
                 const int*   __restrict__ ws_sorted,
                 float4* __restrict__ obox,
                 float*  __restrict__ area,
                 int N)
{
  const int b = blockIdx.y;
  const int i = blockIdx.x * NTHR + threadIdx.x;
  float fimg = getimg(img_i);
  float offs = fimg + 1.0f;
  int orig = ws_sorted[(size_t)b * N + i];
  float4 bb = ((const float4*)(boxes + (size_t)b * N * 4))[orig];
  float off = (float)labels[(size_t)b * N + orig] * offs;
  bb.x = clipf(bb.x, fimg) + off;
  bb.y = clipf(bb.y, fimg) + off;
  bb.z = clipf(bb.z, fimg) + off;
  bb.w = clipf(bb.w, fimg) + off;
  obox[(size_t)b * NBOX + i] = bb;
  area[(size_t)b * NBOX + i] = fmaxf(bb.z - bb.x, 0.0f) * fmaxf(bb.w - bb.y, 0.0f);
}

// =================== kernel M: suppression matrix, 2-D tiled ===================
// block = (row-tile rt: 64 rows) x (col-tile ct: CTW words = CTW*64 cols)
// writes supmat[b][i][w] for w in [max(ct*CTW, rt), min(ct*CTW+CTW, JW))
// also diag[b][i] = supmat[b][i][i>>6] (intra-tile word) when covered.
__global__ __launch_bounds__(256)
void supmat_kernel(const float4* __restrict__ obox,
                   const float*  __restrict__ area,
                   const float*  __restrict__ nms_th,
                   const int*    __restrict__ ws_V,
                   ull* __restrict__ supmat,
                   ull* __restrict__ diag)
{
  __shared__ float4 cbox[CTW * 64];
  __shared__ float  carea[CTW * 64];

  const int bx  = blockIdx.x;          // 0..255: rt = bx&63, ct = bx>>6
  const int rt  = bx & 63;
  const int ct  = bx >> 6;
  const int b   = blockIdx.y;
  const int tid = threadIdx.x;
  const int V   = ws_V[b];
  const int JW  = (V + 63) >> 6;

  const int w0 = (ct * CTW > rt) ? ct * CTW : rt;
  const int w1 = (ct * CTW + CTW < JW) ? ct * CTW + CTW : JW;
  if (rt >= JW || w0 >= w1) return;

  double xt = (double)(*nms_th);
  float  th = (float)(1.0 / (1.0 + exp(-xt)));

  const float4* ob = obox + (size_t)b * NBOX;
  const float*  ar = area + (size_t)b * NBOX;

  const int nstage = (w1 - ct * CTW) * 64;
  for (int e = tid; e < nstage; e += 256) {
    cbox[e]  = ob[ct * CTW * 64 + e];
    carea[e] = ar[ct * CTW * 64 + e];
  }
  __syncthreads();

  const int wave = tid >> 6;
  const int lane = tid & 63;
  for (int rr = 0; rr < 16; ++rr) {
    const int i = rt * 64 + wave * 16 + rr;
    if (i >= V) continue;
    const float4 bi = ob[i];
    const float  ai = ar[i];
    ull* rowp = supmat + ((size_t)b * NBOX + i) * ROWW;
    for (int w = w0; w < w1; ++w) {
      const int cidx = (w - ct * CTW) * 64 + lane;
      float4 bj = cbox[cidx];
      float  aj = carea[cidx];
      const int j = w * 64 + lane;
      float xx1 = fmaxf(bi.x, bj.x);
      float yy1 = fmaxf(bi.y, bj.y);
      float xx2 = fminf(bi.z, bj.z);
      float yy2 = fminf(bi.w, bj.w);
      float inter = fmaxf(xx2 - xx1, 0.0f) * fmaxf(yy2 - yy1, 0.0f);
      float denom = ai + aj;           // ((areas[i]+areas[j]) - inter) + 1e-9, ref order
      denom = denom - inter;
      denom = denom + 1e-9f;
      float iou = inter / denom;
      ull word = __ballot((iou > th) && (j > i));
      if (lane == 0) {
        rowp[w] = word;
        if (w == rt) diag[(size_t)b * NBOX + i] = word;
      }
    }
  }
}

// =================== kernel R: greedy resolve (bit ops) + output ===================
__global__ __launch_bounds__(256)
void resolve_kernel(const float* __restrict__ boxes,
                    const float* __restrict__ scores,
                    const int*   __restrict__ labels,
                    const int*   __restrict__ img_i,
                    float* __restrict__ out,
                    int B, int N,
                    const int* __restrict__ ws_sorted,
                    const int* __restrict__ ws_V,
                    const ull* __restrict__ supmat,
                    const ull* __restrict__ diag)
{
  __shared__ int kept_pos[MAXDET];
  __shared__ int Ksh;

  const int b   = blockIdx.x;
  const int tid = threadIdx.x;
  const int V   = ws_V[b];
  const ull* smat = supmat + (size_t)b * NBOX * ROWW;
  const ull* dg   = diag   + (size_t)b * NBOX;

  if (tid < 64) {
    const int lane = tid;
    ull alive = 0;
    {
      int lo = lane * 64;
      if (V > lo) { int n = V - lo; alive = (n >= 64) ? ~0ull : ((1ull << n) - 1ull); }
    }
    const int JW = (V + 63) >> 6;
    int total = 0;
    for (int t = 0; t < JW; ++t) {
      ull aw = __shfl(alive, t);
      if (!aw) continue;
      ull supby = dg[t * 64 + lane];   // coalesced 512B line
      ull rem = aw;
      ull keptmask = 0;
      bool done = false;
      while (rem) {
        int l = __builtin_ctzll(rem);
        rem &= rem - 1;
        keptmask |= (1ull << l);
        if (lane == 0) kept_pos[total] = t * 64 + l;
        ++total;
        if (total == MAXDET) { done = true; break; }
        ull su = __shfl(supby, l);
        rem &= ~su;
      }
      if (done) break;
      ull acc = 0;
      ull km = keptmask;
      while (km) {
        int l = __builtin_ctzll(km);
        km &= km - 1;
        acc |= smat[(size_t)(t * 64 + l) * ROWW + lane];  // coalesced row
      }
      if (lane > t) alive &= ~acc;
    }
    if (tid == 0) Ksh = total;
  }
  __syncthreads();
  const int K = Ksh;

  float fimg = getimg(img_i);
  const float* bx = boxes  + (size_t)b * N * 4;
  const float* sc = scores + (size_t)b * N;
  const int*   lb = labels + (size_t)b * N;
  const int*   so = ws_sorted + (size_t)b * N;

  float4* obx = (float4*)out;
  float*  osc = out + (size_t)B * MAXDET * 4;
  float*  olb = osc + (size_t)B * MAXDET;
  float*  ovl = olb + (size_t)B * MAXDET;
  for (int r = tid; r < MAXDET; r += 256) {
    size_t slot = (size_t)b * MAXDET + r;
    if (r < K) {
      int i    = kept_pos[r];
      int orig = so[i];
      float4 bb = ((const float4*)bx)[orig];
      bb.x = clipf(bb.x, fimg);
      bb.y = clipf(bb.y, fimg);
      bb.z = clipf(bb.z, fimg);
      bb.w = clipf(bb.w, fimg);
      obx[slot] = bb;
      osc[slot] = sc[orig];
      olb[slot] = (float)lb[orig];
      ovl[slot] = 1.0f;
    } else {
      obx[slot] = make_float4(0.f, 0.f, 0.f, 0.f);
      osc[slot] = 0.0f;
      olb[slot] = 0.0f;
      ovl[slot] = 0.0f;
    }
  }
}

// =================== fallback kernel (round-2 path, used if ws too small) ===================
struct SMB {
  float4       obox[CAP];
  unsigned int keepw[NWORDS];
  int          kept_pos[MAXDET];
  int          scal[4];
};

__global__ __launch_bounds__(NTHR)
void nms_kernel(const float* __restrict__ boxes,
                const float* __restrict__ scores,
                const int*   __restrict__ labels,
                const float* __restrict__ nms_th,
                const float* __restrict__ cls_w,
                const int*   __restrict__ img_i,
                float* __restrict__ out,
                int B, int N,
                const int* __restrict__ ws_sorted,
                const int* __restrict__ ws_V,
                float4* __restrict__ ws_ovf)
{
  __shared__ SMB sm;
  const int b    = blockIdx.x;
  const int tid  = threadIdx.x;

  const float* bx = boxes  + (size_t)b * N * 4;
  const float* sc = scores + (size_t)b * N;
  const int*   lb = labels + (size_t)b * N;
  const int*   so = ws_sorted + (size_t)b * N;

  float fimg = getimg(img_i);
  float off_scale = fimg + 1.0f;
  double xt = (double)(*nms_th);
  float  th = (float)(1.0 / (1.0 + exp(-xt)));

  const int V = ws_V[b];
  if (tid < 4) sm.scal[tid] = 0;

  for (int m = 0; m < 4; ++m) {
    int i = tid + m * NTHR;
    int orig = so[i];
    float4 bb = ((const float4*)bx)[orig];
    float off = (float)lb[orig] * off_scale;
    bb.x = clipf(bb.x, fimg) + off;
    bb.y = clipf(bb.y, fimg) + off;
    bb.z = clipf(bb.z, fimg) + off;
    bb.w = clipf(bb.w, fimg) + off;
    if (i < CAP) sm.obox[i] = bb;
    else         ws_ovf[(size_t)b * (NBOX - CAP) + (i - CAP)] = bb;
  }
  for (int w = tid; w < NWORDS; w += NTHR) {
    int lo = w * 32;
    unsigned val;
    if      (V >= lo + 32) val = 0xFFFFFFFFu;
    else if (V <= lo)      val = 0u;
    else                   val = (1u << (V - lo)) - 1u;
    sm.keepw[w] = val;
  }
  __syncthreads();

  const int nt = (V + 63) >> 6;
  int TR = 0;
  for (int t = 0; t < nt; ++t) {
    if (tid < 64) {
      int i0 = t * 64;
      int me = i0 + tid;
      float4 bb = (me < CAP) ? sm.obox[me]
                             : ws_ovf[(size_t)b * (NBOX - CAP) + (me - CAP)];
      float arJ = fmaxf(bb.z - bb.x, 0.0f) * fmaxf(bb.w - bb.y, 0.0f);
      ull supby = 0;
      for (int l = 0; l < 64; ++l) {
        int i = i0 + l;
        float4 bi = (i < CAP) ? sm.obox[i]
                              : ws_ovf[(size_t)b * (NBOX - CAP) + (i - CAP)];
        float ai = fmaxf(bi.z - bi.x, 0.0f) * fmaxf(bi.w - bi.y, 0.0f);
        float xx1 = fmaxf(bi.x, bb.x);
        float yy1 = fmaxf(bi.y, bb.y);
        float xx2 = fminf(bi.z, bb.z);
        float yy2 = fminf(bi.w, bb.w);
        float inter = fmaxf(xx2 - xx1, 0.0f) * fmaxf(yy2 - yy1, 0.0f);
        float denom = ai + arJ;
        denom = denom - inter;
        denom = denom + 1e-9f;
        float iou = inter / denom;
        if (iou > th) supby |= (1ull << l);
      }
      ull alive = ((ull)sm.keepw[2 * t + 1] << 32) | sm.keepw[2 * t];
      ull rem = alive;
      while (rem) {
        int l = __builtin_ctzll(rem);
        rem &= rem - 1;
        ull sup = __ballot((supby >> l) & 1ull);
        sup &= ((~1ull) << l);
        sup &= alive;
        alive &= ~sup;
        rem   &= ~sup;
      }
      if (tid == 0) {
        sm.keepw[2 * t]     = (unsigned)alive;
        sm.keepw[2 * t + 1] = (unsigned)(alive >> 32);
        atomicAdd(&sm.scal[1], __builtin_popcountll(alive));
      }
    }
    __syncthreads();
    TR = t + 1;
    if (sm.scal[1] >= MAXDET) break;

    int jstart = (t + 1) * 64;
    if (jstart < V) {
      ull alive = ((ull)sm.keepw[2 * t + 1] << 32) | sm.keepw[2 * t];
      if (alive) {
        for (int j = jstart + tid; j < V; j += NTHR) {
          unsigned wj = sm.keepw[j >> 5];
          if (!((wj >> (j & 31)) & 1u)) continue;
          float4 bj = (j < CAP) ? sm.obox[j]
                                : ws_ovf[(size_t)b * (NBOX - CAP) + (j - CAP)];
          float aj = fmaxf(bj.z - bj.x, 0.0f) * fmaxf(bj.w - bj.y, 0.0f);
          ull rem = alive;
          bool suppressed = false;
          while (rem) {
            int l = __builtin_ctzll(rem);
            rem &= rem - 1;
            int i = t * 64 + l;
            float4 bi = (i < CAP) ? sm.obox[i]
                                  : ws_ovf[(size_t)b * (NBOX - CAP) + (i - CAP)];
            float ai = fmaxf(bi.z - bi.x, 0.0f) * fmaxf(bi.w - bi.y, 0.0f);
            float xx1 = fmaxf(bi.x, bj.x);
            float yy1 = fmaxf(bi.y, bj.y);
            float xx2 = fminf(bi.z, bj.z);
            float yy2 = fminf(bi.w, bj.w);
            float inter = fmaxf(xx2 - xx1, 0.0f) * fmaxf(yy2 - yy1, 0.0f);
            float denom = ai + aj;
            denom = denom - inter;
            denom = denom + 1e-9f;
            float iou = inter / denom;
            if (iou > th) { suppressed = true; break; }
          }
          if (suppressed) atomicAnd(&sm.keepw[j >> 5], ~(1u << (j & 31)));
        }
      }
    }
    __syncthreads();
  }

  if (tid < NWORDS && tid >= TR * 2) sm.keepw[tid] = 0;
  __syncthreads();
  if (tid == 0) {
    int r = 0;
    for (int w = 0; w < NWORDS && r < MAXDET; ++w) {
      unsigned bits = sm.keepw[w];
      while (bits && r < MAXDET) {
        int l = __builtin_ctz(bits);
        bits &= bits - 1;
        sm.kept_pos[r++] = w * 32 + l;
      }
    }
    sm.scal[3] = r;
  }
  __syncthreads();
  const int K = sm.scal[3];

  float4* obx = (float4*)out;
  float*  osc = out + (size_t)B * MAXDET * 4;
  float*  olb = osc + (size_t)B * MAXDET;
  float*  ovl = olb + (size_t)B * MAXDET;
  for (int r = tid; r < MAXDET; r += NTHR) {
    size_t slot = (size_t)b * MAXDET + r;
    if (r < K) {
      int i    = sm.kept_pos[r];
      int orig = so[i];
      float4 bb = ((const float4*)bx)[orig];
      bb.x = clipf(bb.x, fimg);
      bb.y = clipf(bb.y, fimg);
      bb.z = clipf(bb.z, fimg);
      bb.w = clipf(bb.w, fimg);
      obx[slot] = bb;
      osc[slot] = sc[orig];
      olb[slot] = (float)lb[orig];
      ovl[slot] = 1.0f;
    } else {
      obx[slot] = make_float4(0.f, 0.f, 0.f, 0.f);
      osc[slot] = 0.0f;
      olb[slot] = 0.0f;
      ovl[slot] = 0.0f;
    }
  }
}

extern "C" void kernel_launch(void* const* d_in, const int* in_sizes, int n_in,
                              void* d_out, int out_size, void* d_ws, size_t ws_size,
                              hipStream_t stream) {
  const float* boxes      = (const float*)d_in[0];
  const float* scores     = (const float*)d_in[1];
  const int*   labels     = (const int*)d_in[2];
  const float* nms_thresh = (const float*)d_in[3];
  const float* cls_w      = (const float*)d_in[4];
  const int*   img_sz     = (const int*)d_in[5];

  int B = out_size / (MAXDET * 7);
  int N = in_sizes[1] / B;               // 4096

  // ws layout
  size_t sz_sorted = (size_t)B * N * 4;
  size_t off_V     = sz_sorted;
  size_t off_obox  = sz_sorted + 1024;
  size_t sz_obox   = (size_t)B * NBOX * 16;
  size_t off_area  = off_obox + sz_obox;
  size_t sz_area   = (size_t)B * NBOX * 4;
  size_t off_diag  = (off_area + sz_area + 255) & ~(size_t)255;
  size_t sz_diag   = (size_t)B * NBOX * 8;
  size_t off_sup   = (off_diag + sz_diag + 255) & ~(size_t)255;
  size_t sz_sup    = (size_t)B * NBOX * ROWW * 8;   // 32 MiB at B=16
  size_t need_fast = off_sup + sz_sup;

  int*    ws_sorted = (int*)d_ws;
  int*    ws_V      = (int*)((char*)d_ws + off_V);

  sort_kernel<<<dim3(B), dim3(NTHR), 0, stream>>>(scores, labels, cls_w,
                                                  ws_sorted, ws_V, N);

  if (ws_size >= need_fast && N == NBOX) {
    float4* obox   = (float4*)((char*)d_ws + off_obox);
    float*  area   = (float*)((char*)d_ws + off_area);
    ull*    diag   = (ull*)((char*)d_ws + off_diag);
    ull*    supmat = (ull*)((char*)d_ws + off_sup);

    prep_kernel<<<dim3(N / NTHR, B), dim3(NTHR), 0, stream>>>(
        boxes, labels, img_sz, ws_sorted, obox, area, N);
    supmat_kernel<<<dim3(256, B), dim3(256), 0, stream>>>(
        obox, area, nms_thresh, ws_V, supmat, diag);
    resolve_kernel<<<dim3(B), dim3(256), 0, stream>>>(
        boxes, scores, labels, img_sz, (float*)d_out, B, N,
        ws_sorted, ws_V, supmat, diag);
  } else {
    float4* ws_ovf = (float4*)((char*)d_ws + sz_sorted + 1024 + sz_obox + sz_area);
    nms_kernel<<<dim3(B), dim3(NTHR), 0, stream>>>(boxes, scores, labels,
                                                   nms_thresh, cls_w, img_sz,
                                                   (float*)d_out, B, N,
                                                   ws_sorted, ws_V, ws_ovf);
  }
}

// Round 5
// 238.698 us; speedup vs baseline: 1.9459x; 1.2207x over previous
//
#include <hip/hip_runtime.h>
#include <math.h>

#define NBOX   4096
#define NTHR   1024
#define MAXDET 300
#define CAP    3968          // fallback path: boxes kept in LDS
#define NWORDS (NBOX / 32)
#define ROWW   64            // ull words per supmat row (4096 bits)
#define CTW    16            // col-tile width in words (1024 boxes, 20KB LDS)

typedef unsigned long long ull;

__device__ __forceinline__ float clipf(float v, float hi) {
  return fminf(fmaxf(v, 0.0f), hi);
}

__device__ __forceinline__ float getimg(const int* img_i) {
  int iv = *img_i;
  return (iv > 0 && iv < (1 << 24)) ? (float)iv : __int_as_float(iv);
}

// XOR swizzle within each 64-word (512B) row of a [64][64] ull tile:
// spreads the stride-512B "diag" column read across 8 banks.
__device__ __forceinline__ int swz(int idx) {
  return (idx & ~63) | ((idx & 63) ^ ((idx >> 6) & 7));
}

// =================== kernel A: build keys + hybrid bitonic sort ===================
struct SMA { ull skey[NBOX]; int vcount; };

__global__ __launch_bounds__(NTHR)
void sort_kernel(const float* __restrict__ scores,
                 const int*   __restrict__ labels,
                 const float* __restrict__ cls_w,
                 int* __restrict__ ws_sorted,
                 int* __restrict__ ws_V,
                 int N)
{
  __shared__ SMA sm;
  const int b   = blockIdx.x;
  const int tid = threadIdx.x;
  const float* sc = scores + (size_t)b * N;
  const int*   lb = labels + (size_t)b * N;

  if (tid == 0) sm.vcount = 0;
  for (int i = tid; i < NBOX; i += NTHR) {
    float s = sc[i];
    ull key = (ull)(0xFFFFFFFFu - (unsigned)i);
    if (s > 0.3f) {                       // SCORE_THRESHOLD, strict >
      float w = s * cls_w[lb[i]];
      unsigned ub = __float_as_uint(w);
      ub = (ub & 0x80000000u) ? ~ub : (ub | 0x80000000u);
      key |= ((ull)ub << 32);
    }
    sm.skey[i] = key;
  }
  __syncthreads();

  const int lane  = tid & 63;
  const int wbase = (tid >> 6) << 8;
  ull v0, v1, v2, v3;

  #define LOADV  { v0 = sm.skey[wbase      + lane]; v1 = sm.skey[wbase + 64 + lane]; \
                   v2 = sm.skey[wbase +128 + lane]; v3 = sm.skey[wbase +192 + lane]; }
  #define STOREV { sm.skey[wbase      + lane] = v0; sm.skey[wbase + 64 + lane] = v1; \
                   sm.skey[wbase +128 + lane] = v2; sm.skey[wbase +192 + lane] = v3; }
  #define CSWAP_REG(va, vb, eo) { int e_ = wbase + (eo) + lane;                      \
      if ((((e_) & k) == 0) ? ((va) < (vb)) : ((va) > (vb))) { ull t_ = (va); (va) = (vb); (vb) = t_; } }
  #define CSWAP_SHFL(vr, eo) { int e_ = wbase + (eo) + lane;                         \
      ull c_ = __shfl_xor((vr), j);                                                  \
      bool km_ = ((((e_) & k) == 0) == ((lane & j) == 0));                           \
      (vr) = km_ ? ((vr) > c_ ? (vr) : c_) : ((vr) < c_ ? (vr) : c_); }
  #define LOCALPHASES(jmax) {                                                        \
      for (int j = (jmax); j >= 1; j >>= 1) {                                        \
        if (j == 128)     { CSWAP_REG(v0, v2, 0);  CSWAP_REG(v1, v3, 64);  }         \
        else if (j == 64) { CSWAP_REG(v0, v1, 0);  CSWAP_REG(v2, v3, 128); }         \
        else { CSWAP_SHFL(v0, 0); CSWAP_SHFL(v1, 64); CSWAP_SHFL(v2, 128); CSWAP_SHFL(v3, 192); } } }

  LOADV;
  for (int k = 2; k <= 256; k <<= 1) { LOCALPHASES(k >> 1); }
  STOREV;
  __syncthreads();

  for (int k = 512; k <= NBOX; k <<= 1) {
    for (int j = k >> 1; j >= 256; j >>= 1) {
      for (int i = tid; i < NBOX; i += NTHR) {
        int l = i ^ j;
        if (l > i) {
          ull a = sm.skey[i], c = sm.skey[l];
          if (((i & k) == 0) ? (a < c) : (a > c)) { sm.skey[i] = c; sm.skey[l] = a; }
        }
      }
      __syncthreads();
    }
    LOADV;
    LOCALPHASES(128);
    STOREV;
    __syncthreads();
  }

  int* wsb = ws_sorted + (size_t)b * N;
  wsb[wbase       + lane] = (int)(0xFFFFFFFFu - (unsigned)v0);
  wsb[wbase +  64 + lane] = (int)(0xFFFFFFFFu - (unsigned)v1);
  wsb[wbase + 128 + lane] = (int)(0xFFFFFFFFu - (unsigned)v2);
  wsb[wbase + 192 + lane] = (int)(0xFFFFFFFFu - (unsigned)v3);
  int vc = (int)((v0 >> 32) != 0) + (int)((v1 >> 32) != 0)
         + (int)((v2 >> 32) != 0) + (int)((v3 >> 32) != 0);
  atomicAdd(&sm.vcount, vc);
  __syncthreads();
  if (tid == 0) ws_V[b] = sm.vcount;
}

// =================== kernel P: gather sorted clipped+offset boxes + areas ===================
__global__ __launch_bounds__(NTHR)
void prep_kernel(const float* __restrict__ boxes,
                 const int*   __restrict__ labels,
                 const int*   __restrict__ img_i,
                 const int*   __restrict__ ws_sorted,
                 float4* __restrict__ obox,
                 float*  __restrict__ area,
                 int N)
{
  const int b = blockIdx.y;
  const int i = blockIdx.x * NTHR + threadIdx.x;
  float fimg = getimg(img_i);
  float offs = fimg + 1.0f;
  int orig = ws_sorted[(size_t)b * N + i];
  float4 bb = ((const float4*)(boxes + (size_t)b * N * 4))[orig];
  float off = (float)labels[(size_t)b * N + orig] * offs;
  bb.x = clipf(bb.x, fimg) + off;
  bb.y = clipf(bb.y, fimg) + off;
  bb.z = clipf(bb.z, fimg) + off;
  bb.w = clipf(bb.w, fimg) + off;
  obox[(size_t)b * NBOX + i] = bb;
  area[(size_t)b * NBOX + i] = fmaxf(bb.z - bb.x, 0.0f) * fmaxf(bb.w - bb.y, 0.0f);
}

// =================== kernel M: suppression matrix, 2-D tiled ===================
// block = (row-tile rt: 64 rows) x (col-tile ct: CTW words)
// writes supmat[b][i][w] for w in [max(ct*CTW, rt), min(ct*CTW+CTW, JW))
__global__ __launch_bounds__(256)
void supmat_kernel(const float4* __restrict__ obox,
                   const float*  __restrict__ area,
                   const float*  __restrict__ nms_th,
                   const int*    __restrict__ ws_V,
                   ull* __restrict__ supmat)
{
  __shared__ float4 cbox[CTW * 64];
  __shared__ float  carea[CTW * 64];
  __shared__ float4 rbox[64];
  __shared__ float  rarea[64];

  const int bx  = blockIdx.x;          // rt = bx&63, ct = bx>>6
  const int rt  = bx & 63;
  const int ct  = bx >> 6;
  const int b   = blockIdx.y;
  const int tid = threadIdx.x;
  const int V   = ws_V[b];
  const int JW  = (V + 63) >> 6;

  const int w0 = (ct * CTW > rt) ? ct * CTW : rt;
  const int w1 = (ct * CTW + CTW < JW) ? ct * CTW + CTW : JW;
  if (rt >= JW || w0 >= w1) return;

  double xt = (double)(*nms_th);
  float  th = (float)(1.0 / (1.0 + exp(-xt)));

  const float4* ob = obox + (size_t)b * NBOX;
  const float*  ar = area + (size_t)b * NBOX;

  const int e1 = (w1 - ct * CTW) * 64;
  for (int e = tid; e < e1; e += 256) {
    cbox[e]  = ob[ct * CTW * 64 + e];
    carea[e] = ar[ct * CTW * 64 + e];
  }
  if (tid < 64) {
    rbox[tid]  = ob[rt * 64 + tid];
    rarea[tid] = ar[rt * 64 + tid];
  }
  __syncthreads();

  const int wave  = tid >> 6;
  const int lane  = tid & 63;
  const int rbase = wave * 16;
  ull* sb = supmat + (size_t)b * NBOX * ROWW;

  for (int w = w0; w < w1; ++w) {
    const float4 bj = cbox[(w - ct * CTW) * 64 + lane];
    const float  aj = carea[(w - ct * CTW) * 64 + lane];
    const int    j  = w * 64 + lane;
    #pragma unroll 4
    for (int rr = 0; rr < 16; ++rr) {
      const int i = rt * 64 + rbase + rr;
      if (i >= V) break;               // rows beyond V never read
      const float4 bi = rbox[rbase + rr];   // LDS broadcast
      const float  ai = rarea[rbase + rr];
      float xx1 = fmaxf(bi.x, bj.x);
      float yy1 = fmaxf(bi.y, bj.y);
      float xx2 = fminf(bi.z, bj.z);
      float yy2 = fminf(bi.w, bj.w);
      float inter = fmaxf(xx2 - xx1, 0.0f) * fmaxf(yy2 - yy1, 0.0f);
      float denom = ai + aj;           // ((areas[i]+areas[j]) - inter) + 1e-9, ref order
      denom = denom - inter;
      denom = denom + 1e-9f;
      float iou = inter / denom;
      ull word = __ballot((iou > th) && (j > i));
      if (lane == 0) sb[(size_t)i * ROWW + w] = word;
    }
  }
}

// =================== kernel R: greedy resolve, LDS-staged tiles + output ===================
__global__ __launch_bounds__(256)
void resolve_kernel(const float* __restrict__ boxes,
                    const float* __restrict__ scores,
                    const int*   __restrict__ labels,
                    const int*   __restrict__ img_i,
                    float* __restrict__ out,
                    int B, int N,
                    const int* __restrict__ ws_sorted,
                    const int* __restrict__ ws_V,
                    const ull* __restrict__ supmat)
{
  __shared__ ull tbuf[2][64 * 64];   // 64 KiB double-buffered tile
  __shared__ int kept_pos[MAXDET];
  __shared__ int ctrl[2];            // [0]=K, [1]=early-done flag

  const int b   = blockIdx.x;
  const int tid = threadIdx.x;
  const int V   = ws_V[b];
  const int JW  = (V + 63) >> 6;
  const ull* smat = supmat + (size_t)b * NBOX * ROWW;

  if (tid == 0) { ctrl[0] = 0; ctrl[1] = 0; }

  // stage tile 0 (rows 0..63 contiguous, 32KB)
  if (JW > 0) {
    ull r[16];
    #pragma unroll
    for (int c = 0; c < 16; ++c) r[c] = smat[tid + c * 256];
    #pragma unroll
    for (int c = 0; c < 16; ++c) tbuf[0][swz(tid + c * 256)] = r[c];
  }
  __syncthreads();

  // wave-0 distributed alive bitmap: lane w owns bits [w*64, w*64+64)
  ull alive = 0;
  if (tid < 64) {
    int lo = tid * 64;
    if (V > lo) { int n = V - lo; alive = (n >= 64) ? ~0ull : ((1ull << n) - 1ull); }
  }
  int total = 0;

  for (int t = 0; t < JW; ++t) {
    const int cur = t & 1;
    // prefetch tile t+1 into registers (loads stay in flight during processing)
    ull r[16];
    const bool pf = (t + 1 < JW);
    if (pf) {
      const ull* src = smat + (size_t)(t + 1) * 4096;
      #pragma unroll
      for (int c = 0; c < 16; ++c) r[c] = src[tid + c * 256];
    }
    // wave 0: walk + apply tile t from LDS
    if (tid < 64) {
      const int lane = tid;
      ull aw = __shfl(alive, t);
      if (aw) {
        ull supby = tbuf[cur][swz(lane * 64 + t)];  // intra-tile suppressed-by word
        ull rem = aw, keptmask = 0;
        bool done = false;
        while (rem) {
          int l = __builtin_ctzll(rem);
          rem &= rem - 1;
          keptmask |= (1ull << l);
          if (lane == 0) kept_pos[total] = t * 64 + l;
          ++total;
          if (total == MAXDET) { done = true; break; }
          rem &= ~__shfl(supby, l);
        }
        // apply kept rows to alive words (4 independent accumulators -> pipelined ds_reads)
        ull a0 = 0, a1 = 0, a2 = 0, a3 = 0;
        ull km = keptmask;
        while (km) {
          int l = __builtin_ctzll(km); km &= km - 1;
          a0 |= tbuf[cur][swz(l * 64 + lane)];
          if (km) { l = __builtin_ctzll(km); km &= km - 1; a1 |= tbuf[cur][swz(l * 64 + lane)]; }
          if (km) { l = __builtin_ctzll(km); km &= km - 1; a2 |= tbuf[cur][swz(l * 64 + lane)]; }
          if (km) { l = __builtin_ctzll(km); km &= km - 1; a3 |= tbuf[cur][swz(l * 64 + lane)]; }
        }
        if (lane > t) alive &= ~((a0 | a1) | (a2 | a3));
        if (done && lane == 0) ctrl[1] = 1;
      }
    }
    __syncthreads();                 // publish ctrl[1]; tile t processing complete
    if (ctrl[1]) break;              // uniform early exit at 300 kept
    if (pf) {
      #pragma unroll
      for (int c = 0; c < 16; ++c) tbuf[cur ^ 1][swz(tid + c * 256)] = r[c];
    }
    __syncthreads();
  }
  if (tid == 0) ctrl[0] = total;
  __syncthreads();
  const int K = ctrl[0];

  // outputs
  float fimg = getimg(img_i);
  const float* bx = boxes  + (size_t)b * N * 4;
  const float* sc = scores + (size_t)b * N;
  const int*   lb = labels + (size_t)b * N;
  const int*   so = ws_sorted + (size_t)b * N;

  float4* obx = (float4*)out;
  float*  osc = out + (size_t)B * MAXDET * 4;
  float*  olb = osc + (size_t)B * MAXDET;
  float*  ovl = olb + (size_t)B * MAXDET;
  for (int rI = tid; rI < MAXDET; rI += 256) {
    size_t slot = (size_t)b * MAXDET + rI;
    if (rI < K) {
      int i    = kept_pos[rI];
      int orig = so[i];
      float4 bb = ((const float4*)bx)[orig];
      bb.x = clipf(bb.x, fimg);
      bb.y = clipf(bb.y, fimg);
      bb.z = clipf(bb.z, fimg);
      bb.w = clipf(bb.w, fimg);
      obx[slot] = bb;
      osc[slot] = sc[orig];
      olb[slot] = (float)lb[orig];
      ovl[slot] = 1.0f;
    } else {
      obx[slot] = make_float4(0.f, 0.f, 0.f, 0.f);
      osc[slot] = 0.0f;
      olb[slot] = 0.0f;
      ovl[slot] = 0.0f;
    }
  }
}

// =================== fallback kernel (round-2 path, used if ws too small) ===================
struct SMB {
  float4       obox[CAP];
  unsigned int keepw[NWORDS];
  int          kept_pos[MAXDET];
  int          scal[4];
};

__global__ __launch_bounds__(NTHR)
void nms_kernel(const float* __restrict__ boxes,
                const float* __restrict__ scores,
                const int*   __restrict__ labels,
                const float* __restrict__ nms_th,
                const float* __restrict__ cls_w,
                const int*   __restrict__ img_i,
                float* __restrict__ out,
                int B, int N,
                const int* __restrict__ ws_sorted,
                const int* __restrict__ ws_V,
                float4* __restrict__ ws_ovf)
{
  __shared__ SMB sm;
  const int b    = blockIdx.x;
  const int tid  = threadIdx.x;

  const float* bx = boxes  + (size_t)b * N * 4;
  const float* sc = scores + (size_t)b * N;
  const int*   lb = labels + (size_t)b * N;
  const int*   so = ws_sorted + (size_t)b * N;

  float fimg = getimg(img_i);
  float off_scale = fimg + 1.0f;
  double xt = (double)(*nms_th);
  float  th = (float)(1.0 / (1.0 + exp(-xt)));

  const int V = ws_V[b];
  if (tid < 4) sm.scal[tid] = 0;

  for (int m = 0; m < 4; ++m) {
    int i = tid + m * NTHR;
    int orig = so[i];
    float4 bb = ((const float4*)bx)[orig];
    float off = (float)lb[orig] * off_scale;
    bb.x = clipf(bb.x, fimg) + off;
    bb.y = clipf(bb.y, fimg) + off;
    bb.z = clipf(bb.z, fimg) + off;
    bb.w = clipf(bb.w, fimg) + off;
    if (i < CAP) sm.obox[i] = bb;
    else         ws_ovf[(size_t)b * (NBOX - CAP) + (i - CAP)] = bb;
  }
  for (int w = tid; w < NWORDS; w += NTHR) {
    int lo = w * 32;
    unsigned val;
    if      (V >= lo + 32) val = 0xFFFFFFFFu;
    else if (V <= lo)      val = 0u;
    else                   val = (1u << (V - lo)) - 1u;
    sm.keepw[w] = val;
  }
  __syncthreads();

  const int nt = (V + 63) >> 6;
  int TR = 0;
  for (int t = 0; t < nt; ++t) {
    if (tid < 64) {
      int i0 = t * 64;
      int me = i0 + tid;
      float4 bb = (me < CAP) ? sm.obox[me]
                             : ws_ovf[(size_t)b * (NBOX - CAP) + (me - CAP)];
      float arJ = fmaxf(bb.z - bb.x, 0.0f) * fmaxf(bb.w - bb.y, 0.0f);
      ull supby = 0;
      for (int l = 0; l < 64; ++l) {
        int i = i0 + l;
        float4 bi = (i < CAP) ? sm.obox[i]
                              : ws_ovf[(size_t)b * (NBOX - CAP) + (i - CAP)];
        float ai = fmaxf(bi.z - bi.x, 0.0f) * fmaxf(bi.w - bi.y, 0.0f);
        float xx1 = fmaxf(bi.x, bb.x);
        float yy1 = fmaxf(bi.y, bb.y);
        float xx2 = fminf(bi.z, bb.z);
        float yy2 = fminf(bi.w, bb.w);
        float inter = fmaxf(xx2 - xx1, 0.0f) * fmaxf(yy2 - yy1, 0.0f);
        float denom = ai + arJ;
        denom = denom - inter;
        denom = denom + 1e-9f;
        float iou = inter / denom;
        if (iou > th) supby |= (1ull << l);
      }
      ull alive = ((ull)sm.keepw[2 * t + 1] << 32) | sm.keepw[2 * t];
      ull rem = alive;
      while (rem) {
        int l = __builtin_ctzll(rem);
        rem &= rem - 1;
        ull sup = __ballot((supby >> l) & 1ull);
        sup &= ((~1ull) << l);
        sup &= alive;
        alive &= ~sup;
        rem   &= ~sup;
      }
      if (tid == 0) {
        sm.keepw[2 * t]     = (unsigned)alive;
        sm.keepw[2 * t + 1] = (unsigned)(alive >> 32);
        atomicAdd(&sm.scal[1], __builtin_popcountll(alive));
      }
    }
    __syncthreads();
    TR = t + 1;
    if (sm.scal[1] >= MAXDET) break;

    int jstart = (t + 1) * 64;
    if (jstart < V) {
      ull alive = ((ull)sm.keepw[2 * t + 1] << 32) | sm.keepw[2 * t];
      if (alive) {
        for (int j = jstart + tid; j < V; j += NTHR) {
          unsigned wj = sm.keepw[j >> 5];
          if (!((wj >> (j & 31)) & 1u)) continue;
          float4 bj = (j < CAP) ? sm.obox[j]
                                : ws_ovf[(size_t)b * (NBOX - CAP) + (j - CAP)];
          float aj = fmaxf(bj.z - bj.x, 0.0f) * fmaxf(bj.w - bj.y, 0.0f);
          ull rem = alive;
          bool suppressed = false;
          while (rem) {
            int l = __builtin_ctzll(rem);
            rem &= rem - 1;
            int i = t * 64 + l;
            float4 bi = (i < CAP) ? sm.obox[i]
                                  : ws_ovf[(size_t)b * (NBOX - CAP) + (i - CAP)];
            float ai = fmaxf(bi.z - bi.x, 0.0f) * fmaxf(bi.w - bi.y, 0.0f);
            float xx1 = fmaxf(bi.x, bj.x);
            float yy1 = fmaxf(bi.y, bj.y);
            float xx2 = fminf(bi.z, bj.z);
            float yy2 = fminf(bi.w, bj.w);
            float inter = fmaxf(xx2 - xx1, 0.0f) * fmaxf(yy2 - yy1, 0.0f);
            float denom = ai + aj;
            denom = denom - inter;
            denom = denom + 1e-9f;
            float iou = inter / denom;
            if (iou > th) { suppressed = true; break; }
          }
          if (suppressed) atomicAnd(&sm.keepw[j >> 5], ~(1u << (j & 31)));
        }
      }
    }
    __syncthreads();
  }

  if (tid < NWORDS && tid >= TR * 2) sm.keepw[tid] = 0;
  __syncthreads();
  if (tid == 0) {
    int r = 0;
    for (int w = 0; w < NWORDS && r < MAXDET; ++w) {
      unsigned bits = sm.keepw[w];
      while (bits && r < MAXDET) {
        int l = __builtin_ctz(bits);
        bits &= bits - 1;
        sm.kept_pos[r++] = w * 32 + l;
      }
    }
    sm.scal[3] = r;
  }
  __syncthreads();
  const int K = sm.scal[3];

  float4* obx = (float4*)out;
  float*  osc = out + (size_t)B * MAXDET * 4;
  float*  olb = osc + (size_t)B * MAXDET;
  float*  ovl = olb + (size_t)B * MAXDET;
  for (int r = tid; r < MAXDET; r += NTHR) {
    size_t slot = (size_t)b * MAXDET + r;
    if (r < K) {
      int i    = sm.kept_pos[r];
      int orig = so[i];
      float4 bb = ((const float4*)bx)[orig];
      bb.x = clipf(bb.x, fimg);
      bb.y = clipf(bb.y, fimg);
      bb.z = clipf(bb.z, fimg);
      bb.w = clipf(bb.w, fimg);
      obx[slot] = bb;
      osc[slot] = sc[orig];
      olb[slot] = (float)lb[orig];
      ovl[slot] = 1.0f;
    } else {
      obx[slot] = make_float4(0.f, 0.f, 0.f, 0.f);
      osc[slot] = 0.0f;
      olb[slot] = 0.0f;
      ovl[slot] = 0.0f;
    }
  }
}

extern "C" void kernel_launch(void* const* d_in, const int* in_sizes, int n_in,
                              void* d_out, int out_size, void* d_ws, size_t ws_size,
                              hipStream_t stream) {
  const float* boxes      = (const float*)d_in[0];
  const float* scores     = (const float*)d_in[1];
  const int*   labels     = (const int*)d_in[2];
  const float* nms_thresh = (const float*)d_in[3];
  const float* cls_w      = (const float*)d_in[4];
  const int*   img_sz     = (const int*)d_in[5];

  int B = out_size / (MAXDET * 7);
  int N = in_sizes[1] / B;               // 4096

  // ws layout
  size_t sz_sorted = (size_t)B * N * 4;
  size_t off_V     = sz_sorted;
  size_t off_obox  = sz_sorted + 1024;
  size_t sz_obox   = (size_t)B * NBOX * 16;
  size_t off_area  = off_obox + sz_obox;
  size_t sz_area   = (size_t)B * NBOX * 4;
  size_t off_sup   = (off_area + sz_area + 255) & ~(size_t)255;
  size_t sz_sup    = (size_t)B * NBOX * ROWW * 8;   // 32 MiB at B=16
  size_t need_fast = off_sup + sz_sup;

  int*    ws_sorted = (int*)d_ws;
  int*    ws_V      = (int*)((char*)d_ws + off_V);

  sort_kernel<<<dim3(B), dim3(NTHR), 0, stream>>>(scores, labels, cls_w,
                                                  ws_sorted, ws_V, N);

  if (ws_size >= need_fast && N == NBOX) {
    float4* obox   = (float4*)((char*)d_ws + off_obox);
    float*  area   = (float*)((char*)d_ws + off_area);
    ull*    supmat = (ull*)((char*)d_ws + off_sup);

    prep_kernel<<<dim3(N / NTHR, B), dim3(NTHR), 0, stream>>>(
        boxes, labels, img_sz, ws_sorted, obox, area, N);
    supmat_kernel<<<dim3(256, B), dim3(256), 0, stream>>>(
        obox, area, nms_thresh, ws_V, supmat);
    resolve_kernel<<<dim3(B), dim3(256), 0, stream>>>(
        boxes, scores, labels, img_sz, (float*)d_out, B, N,
        ws_sorted, ws_V, supmat);
  } else {
    float4* ws_ovf = (float4*)((char*)d_ws + sz_sorted + 1024 + sz_obox + sz_area);
    nms_kernel<<<dim3(B), dim3(NTHR), 0, stream>>>(boxes, scores, labels,
                                                   nms_thresh, cls_w, img_sz,
                                                   (float*)d_out, B, N,
                                                   ws_sorted, ws_V, ws_ovf);
  }
}

// Round 6
// 178.608 us; speedup vs baseline: 2.6006x; 1.3364x over previous
//
#include <hip/hip_runtime.h>
#include <math.h>

#define NBOX   4096
#define NTHR   1024
#define MAXDET 300
#define CAP    3968          // fallback path: boxes kept in LDS
#define NWORDS (NBOX / 32)
#define ROWW   64            // ull words per supmat row (4096 bits)
#define CTW    16            // col-tile width in words per supmat block

typedef unsigned long long ull;

__device__ __forceinline__ float clipf(float v, float hi) {
  return fminf(fmaxf(v, 0.0f), hi);
}

__device__ __forceinline__ float getimg(const int* img_i) {
  int iv = *img_i;
  return (iv > 0 && iv < (1 << 24)) ? (float)iv : __int_as_float(iv);
}

// =================== kernel A: build keys + hybrid bitonic sort ===================
struct SMA { ull skey[NBOX]; int vcount; };

__global__ __launch_bounds__(NTHR)
void sort_kernel(const float* __restrict__ scores,
                 const int*   __restrict__ labels,
                 const float* __restrict__ cls_w,
                 int* __restrict__ ws_sorted,
                 int* __restrict__ ws_V,
                 int* __restrict__ ws_done,
                 int N)
{
  __shared__ SMA sm;
  const int b   = blockIdx.x;
  const int tid = threadIdx.x;
  const float* sc = scores + (size_t)b * N;
  const int*   lb = labels + (size_t)b * N;

  if (tid == 0) { sm.vcount = 0; ws_done[b] = 0; }   // reset per-call state
  for (int i = tid; i < NBOX; i += NTHR) {
    float s = sc[i];
    ull key = (ull)(0xFFFFFFFFu - (unsigned)i);
    if (s > 0.3f) {                       // SCORE_THRESHOLD, strict >
      float w = s * cls_w[lb[i]];
      unsigned ub = __float_as_uint(w);
      ub = (ub & 0x80000000u) ? ~ub : (ub | 0x80000000u);
      key |= ((ull)ub << 32);
    }
    sm.skey[i] = key;
  }
  __syncthreads();

  const int lane  = tid & 63;
  const int wbase = (tid >> 6) << 8;
  ull v0, v1, v2, v3;

  #define LOADV  { v0 = sm.skey[wbase      + lane]; v1 = sm.skey[wbase + 64 + lane]; \
                   v2 = sm.skey[wbase +128 + lane]; v3 = sm.skey[wbase +192 + lane]; }
  #define STOREV { sm.skey[wbase      + lane] = v0; sm.skey[wbase + 64 + lane] = v1; \
                   sm.skey[wbase +128 + lane] = v2; sm.skey[wbase +192 + lane] = v3; }
  #define CSWAP_REG(va, vb, eo) { int e_ = wbase + (eo) + lane;                      \
      if ((((e_) & k) == 0) ? ((va) < (vb)) : ((va) > (vb))) { ull t_ = (va); (va) = (vb); (vb) = t_; } }
  #define CSWAP_SHFL(vr, eo) { int e_ = wbase + (eo) + lane;                         \
      ull c_ = __shfl_xor((vr), j);                                                  \
      bool km_ = ((((e_) & k) == 0) == ((lane & j) == 0));                           \
      (vr) = km_ ? ((vr) > c_ ? (vr) : c_) : ((vr) < c_ ? (vr) : c_); }
  #define LOCALPHASES(jmax) {                                                        \
      for (int j = (jmax); j >= 1; j >>= 1) {                                        \
        if (j == 128)     { CSWAP_REG(v0, v2, 0);  CSWAP_REG(v1, v3, 64);  }         \
        else if (j == 64) { CSWAP_REG(v0, v1, 0);  CSWAP_REG(v2, v3, 128); }         \
        else { CSWAP_SHFL(v0, 0); CSWAP_SHFL(v1, 64); CSWAP_SHFL(v2, 128); CSWAP_SHFL(v3, 192); } } }

  LOADV;
  for (int k = 2; k <= 256; k <<= 1) { LOCALPHASES(k >> 1); }
  STOREV;
  __syncthreads();

  for (int k = 512; k <= NBOX; k <<= 1) {
    for (int j = k >> 1; j >= 256; j >>= 1) {
      for (int i = tid; i < NBOX; i += NTHR) {
        int l = i ^ j;
        if (l > i) {
          ull a = sm.skey[i], c = sm.skey[l];
          if (((i & k) == 0) ? (a < c) : (a > c)) { sm.skey[i] = c; sm.skey[l] = a; }
        }
      }
      __syncthreads();
    }
    LOADV;
    LOCALPHASES(128);
    STOREV;
    __syncthreads();
  }

  int* wsb = ws_sorted + (size_t)b * N;
  wsb[wbase       + lane] = (int)(0xFFFFFFFFu - (unsigned)v0);
  wsb[wbase +  64 + lane] = (int)(0xFFFFFFFFu - (unsigned)v1);
  wsb[wbase + 128 + lane] = (int)(0xFFFFFFFFu - (unsigned)v2);
  wsb[wbase + 192 + lane] = (int)(0xFFFFFFFFu - (unsigned)v3);
  int vc = (int)((v0 >> 32) != 0) + (int)((v1 >> 32) != 0)
         + (int)((v2 >> 32) != 0) + (int)((v3 >> 32) != 0);
  atomicAdd(&sm.vcount, vc);
  __syncthreads();
  if (tid == 0) ws_V[b] = sm.vcount;
}

// =================== kernel P: gather sorted clipped+offset boxes + areas ===================
__global__ __launch_bounds__(NTHR)
void prep_kernel(const float* __restrict__ boxes,
                 const int*   __restrict__ labels,
                 const int*   __restrict__ img_i,
                 const int*   __restrict__ ws_sorted,
                 float4* __restrict__ obox,
                 float*  __restrict__ area,
                 int N)
{
  const int b = blockIdx.y;
  const int i = blockIdx.x * NTHR + threadIdx.x;
  float fimg = getimg(img_i);
  float offs = fimg + 1.0f;
  int orig = ws_sorted[(size_t)b * N + i];
  float4 bb = ((const float4*)(boxes + (size_t)b * N * 4))[orig];
  float off = (float)labels[(size_t)b * N + orig] * offs;
  bb.x = clipf(bb.x, fimg) + off;
  bb.y = clipf(bb.y, fimg) + off;
  bb.z = clipf(bb.z, fimg) + off;
  bb.w = clipf(bb.w, fimg) + off;
  obox[(size_t)b * NBOX + i] = bb;
  area[(size_t)b * NBOX + i] = fmaxf(bb.z - bb.x, 0.0f) * fmaxf(bb.w - bb.y, 0.0f);
}

// =================== kernel M: suppression matrix CHUNK ===================
// chunk covers words [wlo, wlo + ngroups*CTW); rows = tiles [0, c1_tiles)
// block: rt = bx % c1_tiles, group g = bx / c1_tiles -> words [wlo+g*CTW, +CTW)
// per-batch early exit via ws_done.
__global__ __launch_bounds__(256)
void supmat_chunk(const float4* __restrict__ obox,
                  const float*  __restrict__ area,
                  const float*  __restrict__ nms_th,
                  const int*    __restrict__ ws_V,
                  const int*    __restrict__ ws_done,
                  ull* __restrict__ supmat,
                  int c1_tiles, int wlo)
{
  __shared__ float4 cbox[CTW * 64];
  __shared__ float  carea[CTW * 64];
  __shared__ float4 rbox[64];
  __shared__ float  rarea[64];

  const int b   = blockIdx.y;
  if (ws_done[b]) return;
  const int rt  = blockIdx.x % c1_tiles;
  const int g   = blockIdx.x / c1_tiles;
  const int tid = threadIdx.x;
  const int V   = ws_V[b];
  const int JW  = (V + 63) >> 6;

  const int wlo_g = wlo + g * CTW;
  const int w0 = (wlo_g > rt) ? wlo_g : rt;
  const int w1 = (wlo_g + CTW < JW) ? wlo_g + CTW : JW;
  if (rt >= JW || w0 >= w1) return;

  double xt = (double)(*nms_th);
  float  th = (float)(1.0 / (1.0 + exp(-xt)));

  const float4* ob = obox + (size_t)b * NBOX;
  const float*  ar = area + (size_t)b * NBOX;

  const int e1 = (w1 - w0) * 64;
  for (int e = tid; e < e1; e += 256) {
    cbox[e]  = ob[w0 * 64 + e];
    carea[e] = ar[w0 * 64 + e];
  }
  if (tid < 64) {
    rbox[tid]  = ob[rt * 64 + tid];
    rarea[tid] = ar[rt * 64 + tid];
  }
  __syncthreads();

  const int wave  = tid >> 6;
  const int lane  = tid & 63;
  const int rbase = wave * 16;
  ull* sb = supmat + (size_t)b * NBOX * ROWW;

  for (int w = w0; w < w1; ++w) {
    const float4 bj = cbox[(w - w0) * 64 + lane];
    const float  aj = carea[(w - w0) * 64 + lane];
    const int    j  = w * 64 + lane;
    #pragma unroll 4
    for (int rr = 0; rr < 16; ++rr) {
      const int i = rt * 64 + rbase + rr;
      if (i >= V) break;               // rows beyond V never read
      const float4 bi = rbox[rbase + rr];   // LDS broadcast
      const float  ai = rarea[rbase + rr];
      float xx1 = fmaxf(bi.x, bj.x);
      float yy1 = fmaxf(bi.y, bj.y);
      float xx2 = fminf(bi.z, bj.z);
      float yy2 = fminf(bi.w, bj.w);
      float inter = fmaxf(xx2 - xx1, 0.0f) * fmaxf(yy2 - yy1, 0.0f);
      float denom = ai + aj;           // ((areas[i]+areas[j]) - inter) + 1e-9, ref order
      denom = denom - inter;
      denom = denom + 1e-9f;
      float iou = inter / denom;
      ull word = __ballot((iou > th) && (j > i));
      if (lane == 0) sb[(size_t)i * ROWW + w] = word;
    }
  }
}

// =================== kernel R: greedy resolve CHUNK (tiles [t0,t1)) ===================
// State across chunks (in ws): done[b], total[b], kept[b][MAXDET].
// Catch-up: alive[w] for w in [t0,t1) = init(w) & ~OR_{kept so far}(row[w]).
template <int W>   // W = t1 - t0 words (16 or 32)
__global__ __launch_bounds__(256)
void resolve_chunk(const float* __restrict__ boxes,
                   const float* __restrict__ scores,
                   const int*   __restrict__ labels,
                   const int*   __restrict__ img_i,
                   float* __restrict__ out,
                   int B, int N,
                   const int* __restrict__ ws_sorted,
                   const int* __restrict__ ws_V,
                   const ull* __restrict__ supmat,
                   int* __restrict__ ws_done,
                   int* __restrict__ ws_total,
                   int* __restrict__ ws_kept,
                   int t0, int t1)
{
  __shared__ ull tbuf[2][64 * W];     // 16KB (W=16) / 32KB (W=32), double-buffered
  __shared__ ull comb[4][32];
  __shared__ int kept_sh[MAXDET];
  __shared__ int ctrl[2];             // [0]=total, [1]=hit-300 flag

  const int b = blockIdx.x;
  if (ws_done[b]) return;             // outputs already written by earlier chunk
  const int tid  = threadIdx.x;
  const int wave = tid >> 6;
  const int lane = tid & 63;
  const int V    = ws_V[b];
  const int JW   = (V + 63) >> 6;
  const ull* smat = supmat + (size_t)b * NBOX * ROWW;
  int* kg = ws_kept + (size_t)b * MAXDET;

  const int total_in = (t0 == 0) ? 0 : ws_total[b];

  // ---- catch-up: OR of kept rows over this chunk's words (all 4 waves) ----
  if (t0 > 0) {
    ull acc = 0;
    for (int k = wave; k < total_in; k += 4) {
      int r = kg[k];
      if (lane < W) acc |= smat[(size_t)r * ROWW + t0 + lane];
    }
    if (lane < 32) comb[wave][lane] = (lane < W) ? acc : 0ull;
  }
  if (tid == 0) { ctrl[0] = total_in; ctrl[1] = 0; }
  __syncthreads();

  // wave-0 alive registers: lane w (< W) owns global word t0+w
  ull alive = 0;
  if (wave == 0 && lane < W) {
    int lo = (t0 + lane) * 64;
    if (V > lo) { int n = V - lo; alive = (n >= 64) ? ~0ull : ((1ull << n) - 1ull); }
    if (t0 > 0) alive &= ~(comb[0][lane] | comb[1][lane] | comb[2][lane] | comb[3][lane]);
  }
  int total = total_in;
  const int tmax = (t1 < JW) ? t1 : JW;
  const int cw   = (lane < W) ? lane : 0;   // safe word-lane for LDS reads

  // stage first tile (rows 64 x words [t0,t1), swizzled)
  if (t0 < tmax) {
    const ull* src = smat + (size_t)t0 * 64 * ROWW + t0;
    #pragma unroll
    for (int c = 0; c < W / 4; ++c) {
      int e = tid + c * 256;
      int row = e / W, w = e % W;
      tbuf[0][row * W + (w ^ (row & (W - 1)))] = src[(size_t)row * ROWW + w];
    }
  }
  __syncthreads();

  for (int t = t0; t < tmax; ++t) {
    const int cur = (t - t0) & 1;
    ull r[W / 4];
    const bool pf = (t + 1 < tmax);
    if (pf) {                          // prefetch next tile into registers
      const ull* src = smat + (size_t)(t + 1) * 64 * ROWW + t0;
      #pragma unroll
      for (int c = 0; c < W / 4; ++c) {
        int e = tid + c * 256;
        int row = e / W, w = e % W;
        r[c] = src[(size_t)row * ROWW + w];
      }
    }
    if (wave == 0) {
      ull aw = __shfl(alive, t - t0);
      if (aw) {
        ull supby = tbuf[cur][lane * W + ((t - t0) ^ (lane & (W - 1)))];
        ull rem = aw, keptmask = 0;
        bool done = false;
        while (rem) {
          int l = __builtin_ctzll(rem);
          rem &= rem - 1;
          keptmask |= (1ull << l);
          if (lane == 0) { kept_sh[total] = t * 64 + l; kg[total] = t * 64 + l; }
          ++total;
          if (total == MAXDET) { done = true; break; }
          rem &= ~__shfl(supby, l);
        }
        // apply kept rows to later words (4 accumulators -> pipelined ds_reads)
        ull a0 = 0, a1 = 0, a2 = 0, a3 = 0;
        ull km = keptmask;
        while (km) {
          int l = __builtin_ctzll(km); km &= km - 1;
          a0 |= tbuf[cur][l * W + (cw ^ (l & (W - 1)))];
          if (km) { l = __builtin_ctzll(km); km &= km - 1; a1 |= tbuf[cur][l * W + (cw ^ (l & (W - 1)))]; }
          if (km) { l = __builtin_ctzll(km); km &= km - 1; a2 |= tbuf[cur][l * W + (cw ^ (l & (W - 1)))]; }
          if (km) { l = __builtin_ctzll(km); km &= km - 1; a3 |= tbuf[cur][l * W + (cw ^ (l & (W - 1)))]; }
        }
        if (lane < W && (t0 + lane) > t) alive &= ~((a0 | a1) | (a2 | a3));
        if (done && lane == 0) ctrl[1] = 1;
      }
      if (lane == 0) ctrl[0] = total;
    }
    __syncthreads();
    if (ctrl[1]) break;                // uniform early exit at 300 kept
    if (pf) {
      #pragma unroll
      for (int c = 0; c < W / 4; ++c) {
        int e = tid + c * 256;
        int row = e / W, w = e % W;
        tbuf[cur ^ 1][row * W + (w ^ (row & (W - 1)))] = r[c];
      }
    }
    __syncthreads();
  }

  const int K = ctrl[0];
  const bool finished = (ctrl[1] != 0) || (t1 >= JW);
  if (!finished) {
    if (tid == 0) ws_total[b] = K;     // kept list already appended to ws
    return;
  }
  if (tid == 0) ws_done[b] = 1;

  // ---- outputs ----
  float fimg = getimg(img_i);
  const float* bx = boxes  + (size_t)b * N * 4;
  const float* sc = scores + (size_t)b * N;
  const int*   lb = labels + (size_t)b * N;
  const int*   so = ws_sorted + (size_t)b * N;

  float4* obx = (float4*)out;
  float*  osc = out + (size_t)B * MAXDET * 4;
  float*  olb = osc + (size_t)B * MAXDET;
  float*  ovl = olb + (size_t)B * MAXDET;
  for (int rI = tid; rI < MAXDET; rI += 256) {
    size_t slot = (size_t)b * MAXDET + rI;
    if (rI < K) {
      int i    = (rI < total_in) ? kg[rI] : kept_sh[rI];
      int orig = so[i];
      float4 bb = ((const float4*)bx)[orig];
      bb.x = clipf(bb.x, fimg);
      bb.y = clipf(bb.y, fimg);
      bb.z = clipf(bb.z, fimg);
      bb.w = clipf(bb.w, fimg);
      obx[slot] = bb;
      osc[slot] = sc[orig];
      olb[slot] = (float)lb[orig];
      ovl[slot] = 1.0f;
    } else {
      obx[slot] = make_float4(0.f, 0.f, 0.f, 0.f);
      osc[slot] = 0.0f;
      olb[slot] = 0.0f;
      ovl[slot] = 0.0f;
    }
  }
}

// =================== fallback kernel (round-2 path, used if ws too small) ===================
struct SMB {
  float4       obox[CAP];
  unsigned int keepw[NWORDS];
  int          kept_pos[MAXDET];
  int          scal[4];
};

__global__ __launch_bounds__(NTHR)
void nms_kernel(const float* __restrict__ boxes,
                const float* __restrict__ scores,
                const int*   __restrict__ labels,
                const float* __restrict__ nms_th,
                const float* __restrict__ cls_w,
                const int*   __restrict__ img_i,
                float* __restrict__ out,
                int B, int N,
                const int* __restrict__ ws_sorted,
                const int* __restrict__ ws_V,
                float4* __restrict__ ws_ovf)
{
  __shared__ SMB sm;
  const int b    = blockIdx.x;
  const int tid  = threadIdx.x;

  const float* bx = boxes  + (size_t)b * N * 4;
  const float* sc = scores + (size_t)b * N;
  const int*   lb = labels + (size_t)b * N;
  const int*   so = ws_sorted + (size_t)b * N;

  float fimg = getimg(img_i);
  float off_scale = fimg + 1.0f;
  double xt = (double)(*nms_th);
  float  th = (float)(1.0 / (1.0 + exp(-xt)));

  const int V = ws_V[b];
  if (tid < 4) sm.scal[tid] = 0;

  for (int m = 0; m < 4; ++m) {
    int i = tid + m * NTHR;
    int orig = so[i];
    float4 bb = ((const float4*)bx)[orig];
    float off = (float)lb[orig] * off_scale;
    bb.x = clipf(bb.x, fimg) + off;
    bb.y = clipf(bb.y, fimg) + off;
    bb.z = clipf(bb.z, fimg) + off;
    bb.w = clipf(bb.w, fimg) + off;
    if (i < CAP) sm.obox[i] = bb;
    else         ws_ovf[(size_t)b * (NBOX - CAP) + (i - CAP)] = bb;
  }
  for (int w = tid; w < NWORDS; w += NTHR) {
    int lo = w * 32;
    unsigned val;
    if      (V >= lo + 32) val = 0xFFFFFFFFu;
    else if (V <= lo)      val = 0u;
    else                   val = (1u << (V - lo)) - 1u;
    sm.keepw[w] = val;
  }
  __syncthreads();

  const int nt = (V + 63) >> 6;
  int TR = 0;
  for (int t = 0; t < nt; ++t) {
    if (tid < 64) {
      int i0 = t * 64;
      int me = i0 + tid;
      float4 bb = (me < CAP) ? sm.obox[me]
                             : ws_ovf[(size_t)b * (NBOX - CAP) + (me - CAP)];
      float arJ = fmaxf(bb.z - bb.x, 0.0f) * fmaxf(bb.w - bb.y, 0.0f);
      ull supby = 0;
      for (int l = 0; l < 64; ++l) {
        int i = i0 + l;
        float4 bi = (i < CAP) ? sm.obox[i]
                              : ws_ovf[(size_t)b * (NBOX - CAP) + (i - CAP)];
        float ai = fmaxf(bi.z - bi.x, 0.0f) * fmaxf(bi.w - bi.y, 0.0f);
        float xx1 = fmaxf(bi.x, bb.x);
        float yy1 = fmaxf(bi.y, bb.y);
        float xx2 = fminf(bi.z, bb.z);
        float yy2 = fminf(bi.w, bb.w);
        float inter = fmaxf(xx2 - xx1, 0.0f) * fmaxf(yy2 - yy1, 0.0f);
        float denom = ai + arJ;
        denom = denom - inter;
        denom = denom + 1e-9f;
        float iou = inter / denom;
        if (iou > th) supby |= (1ull << l);
      }
      ull alive = ((ull)sm.keepw[2 * t + 1] << 32) | sm.keepw[2 * t];
      ull rem = alive;
      while (rem) {
        int l = __builtin_ctzll(rem);
        rem &= rem - 1;
        ull sup = __ballot((supby >> l) & 1ull);
        sup &= ((~1ull) << l);
        sup &= alive;
        alive &= ~sup;
        rem   &= ~sup;
      }
      if (tid == 0) {
        sm.keepw[2 * t]     = (unsigned)alive;
        sm.keepw[2 * t + 1] = (unsigned)(alive >> 32);
        atomicAdd(&sm.scal[1], __builtin_popcountll(alive));
      }
    }
    __syncthreads();
    TR = t + 1;
    if (sm.scal[1] >= MAXDET) break;

    int jstart = (t + 1) * 64;
    if (jstart < V) {
      ull alive = ((ull)sm.keepw[2 * t + 1] << 32) | sm.keepw[2 * t];
      if (alive) {
        for (int j = jstart + tid; j < V; j += NTHR) {
          unsigned wj = sm.keepw[j >> 5];
          if (!((wj >> (j & 31)) & 1u)) continue;
          float4 bj = (j < CAP) ? sm.obox[j]
                                : ws_ovf[(size_t)b * (NBOX - CAP) + (j - CAP)];
          float aj = fmaxf(bj.z - bj.x, 0.0f) * fmaxf(bj.w - bj.y, 0.0f);
          ull rem = alive;
          bool suppressed = false;
          while (rem) {
            int l = __builtin_ctzll(rem);
            rem &= rem - 1;
            int i = t * 64 + l;
            float4 bi = (i < CAP) ? sm.obox[i]
                                  : ws_ovf[(size_t)b * (NBOX - CAP) + (i - CAP)];
            float ai = fmaxf(bi.z - bi.x, 0.0f) * fmaxf(bi.w - bi.y, 0.0f);
            float xx1 = fmaxf(bi.x, bj.x);
            float yy1 = fmaxf(bi.y, bj.y);
            float xx2 = fminf(bi.z, bj.z);
            float yy2 = fminf(bi.w, bj.w);
            float inter = fmaxf(xx2 - xx1, 0.0f) * fmaxf(yy2 - yy1, 0.0f);
            float denom = ai + aj;
            denom = denom - inter;
            denom = denom + 1e-9f;
            float iou = inter / denom;
            if (iou > th) { suppressed = true; break; }
          }
          if (suppressed) atomicAnd(&sm.keepw[j >> 5], ~(1u << (j & 31)));
        }
      }
    }
    __syncthreads();
  }

  if (tid < NWORDS && tid >= TR * 2) sm.keepw[tid] = 0;
  __syncthreads();
  if (tid == 0) {
    int r = 0;
    for (int w = 0; w < NWORDS && r < MAXDET; ++w) {
      unsigned bits = sm.keepw[w];
      while (bits && r < MAXDET) {
        int l = __builtin_ctz(bits);
        bits &= bits - 1;
        sm.kept_pos[r++] = w * 32 + l;
      }
    }
    sm.scal[3] = r;
  }
  __syncthreads();
  const int K = sm.scal[3];

  float4* obx = (float4*)out;
  float*  osc = out + (size_t)B * MAXDET * 4;
  float*  olb = osc + (size_t)B * MAXDET;
  float*  ovl = olb + (size_t)B * MAXDET;
  for (int r = tid; r < MAXDET; r += NTHR) {
    size_t slot = (size_t)b * MAXDET + r;
    if (r < K) {
      int i    = sm.kept_pos[r];
      int orig = so[i];
      float4 bb = ((const float4*)bx)[orig];
      bb.x = clipf(bb.x, fimg);
      bb.y = clipf(bb.y, fimg);
      bb.z = clipf(bb.z, fimg);
      bb.w = clipf(bb.w, fimg);
      obx[slot] = bb;
      osc[slot] = sc[orig];
      olb[slot] = (float)lb[orig];
      ovl[slot] = 1.0f;
    } else {
      obx[slot] = make_float4(0.f, 0.f, 0.f, 0.f);
      osc[slot] = 0.0f;
      olb[slot] = 0.0f;
      ovl[slot] = 0.0f;
    }
  }
}

extern "C" void kernel_launch(void* const* d_in, const int* in_sizes, int n_in,
                              void* d_out, int out_size, void* d_ws, size_t ws_size,
                              hipStream_t stream) {
  const float* boxes      = (const float*)d_in[0];
  const float* scores     = (const float*)d_in[1];
  const int*   labels     = (const int*)d_in[2];
  const float* nms_thresh = (const float*)d_in[3];
  const float* cls_w      = (const float*)d_in[4];
  const int*   img_sz     = (const int*)d_in[5];

  int B = out_size / (MAXDET * 7);
  int N = in_sizes[1] / B;               // 4096

  // ws layout
  size_t sz_sorted = (size_t)B * N * 4;
  size_t off_V     = sz_sorted;
  size_t off_obox  = sz_sorted + 1024;
  size_t sz_obox   = (size_t)B * NBOX * 16;
  size_t off_area  = off_obox + sz_obox;
  size_t sz_area   = (size_t)B * NBOX * 4;
  size_t off_done  = (off_area + sz_area + 255) & ~(size_t)255;
  size_t off_total = off_done + (size_t)B * 4;
  size_t off_kept  = off_total + (size_t)B * 4;
  size_t off_sup   = (off_kept + (size_t)B * MAXDET * 4 + 255) & ~(size_t)255;
  size_t sz_sup    = (size_t)B * NBOX * ROWW * 8;   // 32 MiB at B=16
  size_t need_fast = off_sup + sz_sup;

  int* ws_sorted = (int*)d_ws;
  int* ws_V      = (int*)((char*)d_ws + off_V);
  int* ws_done   = (int*)((char*)d_ws + off_done);

  sort_kernel<<<dim3(B), dim3(NTHR), 0, stream>>>(scores, labels, cls_w,
                                                  ws_sorted, ws_V, ws_done, N);

  if (ws_size >= need_fast && N == NBOX) {
    float4* obox     = (float4*)((char*)d_ws + off_obox);
    float*  area     = (float*)((char*)d_ws + off_area);
    int*    ws_total = (int*)((char*)d_ws + off_total);
    int*    ws_kept  = (int*)((char*)d_ws + off_kept);
    ull*    supmat   = (ull*)((char*)d_ws + off_sup);

    prep_kernel<<<dim3(N / NTHR, B), dim3(NTHR), 0, stream>>>(
        boxes, labels, img_sz, ws_sorted, obox, area, N);

    // chunk 0: tiles [0,16)
    supmat_chunk<<<dim3(16, B), dim3(256), 0, stream>>>(
        obox, area, nms_thresh, ws_V, ws_done, supmat, 16, 0);
    resolve_chunk<16><<<dim3(B), dim3(256), 0, stream>>>(
        boxes, scores, labels, img_sz, (float*)d_out, B, N,
        ws_sorted, ws_V, supmat, ws_done, ws_total, ws_kept, 0, 16);

    // chunk 1: tiles [16,32)
    supmat_chunk<<<dim3(32, B), dim3(256), 0, stream>>>(
        obox, area, nms_thresh, ws_V, ws_done, supmat, 32, 16);
    resolve_chunk<16><<<dim3(B), dim3(256), 0, stream>>>(
        boxes, scores, labels, img_sz, (float*)d_out, B, N,
        ws_sorted, ws_V, supmat, ws_done, ws_total, ws_kept, 16, 32);

    // chunk 2: tiles [32,64)
    supmat_chunk<<<dim3(128, B), dim3(256), 0, stream>>>(
        obox, area, nms_thresh, ws_V, ws_done, supmat, 64, 32);
    resolve_chunk<32><<<dim3(B), dim3(256), 0, stream>>>(
        boxes, scores, labels, img_sz, (float*)d_out, B, N,
        ws_sorted, ws_V, supmat, ws_done, ws_total, ws_kept, 32, 64);
  } else {
    float4* ws_ovf = (float4*)((char*)d_ws + sz_sorted + 1024 + sz_obox + sz_area);
    nms_kernel<<<dim3(B), dim3(NTHR), 0, stream>>>(boxes, scores, labels,
                                                   nms_thresh, cls_w, img_sz,
                                                   (float*)d_out, B, N,
                                                   ws_sorted, ws_V, ws_ovf);
  }
}

// Round 8
// 174.843 us; speedup vs baseline: 2.6566x; 1.0215x over previous
//
#include <hip/hip_runtime.h>
#include <math.h>

#define NBOX   4096
#define NTHR   1024
#define MAXDET 300
#define CAP    3968          // fallback path: boxes kept in LDS
#define NWORDS (NBOX / 32)
#define ROWW   64            // ull words per supmat row (4096 bits)
#define CTW    16            // col-tile width in words per supmat block

typedef unsigned long long ull;

__device__ __forceinline__ float clipf(float v, float hi) {
  return fminf(fmaxf(v, 0.0f), hi);
}

__device__ __forceinline__ float getimg(const int* img_i) {
  int iv = *img_i;
  return (iv > 0 && iv < (1 << 24)) ? (float)iv : __int_as_float(iv);
}

// =================== kernel A: build keys + hybrid bitonic sort ===================
struct SMA { ull skey[NBOX]; int vcount; };

__global__ __launch_bounds__(NTHR)
void sort_kernel(const float* __restrict__ scores,
                 const int*   __restrict__ labels,
                 const float* __restrict__ cls_w,
                 int* __restrict__ ws_sorted,
                 int* __restrict__ ws_V,
                 int* __restrict__ ws_done,
                 int N)
{
  __shared__ SMA sm;
  const int b   = blockIdx.x;
  const int tid = threadIdx.x;
  const float* sc = scores + (size_t)b * N;
  const int*   lb = labels + (size_t)b * N;

  if (tid == 0) { sm.vcount = 0; ws_done[b] = 0; }   // reset per-call state
  for (int i = tid; i < NBOX; i += NTHR) {
    float s = sc[i];
    ull key = (ull)(0xFFFFFFFFu - (unsigned)i);
    if (s > 0.3f) {                       // SCORE_THRESHOLD, strict >
      float w = s * cls_w[lb[i]];
      unsigned ub = __float_as_uint(w);
      ub = (ub & 0x80000000u) ? ~ub : (ub | 0x80000000u);
      key |= ((ull)ub << 32);
    }
    sm.skey[i] = key;
  }
  __syncthreads();

  const int lane  = tid & 63;
  const int wbase = (tid >> 6) << 8;
  ull v0, v1, v2, v3;

  #define LOADV  { v0 = sm.skey[wbase      + lane]; v1 = sm.skey[wbase + 64 + lane]; \
                   v2 = sm.skey[wbase +128 + lane]; v3 = sm.skey[wbase +192 + lane]; }
  #define STOREV { sm.skey[wbase      + lane] = v0; sm.skey[wbase + 64 + lane] = v1; \
                   sm.skey[wbase +128 + lane] = v2; sm.skey[wbase +192 + lane] = v3; }
  #define CSWAP_REG(va, vb, eo) { int e_ = wbase + (eo) + lane;                      \
      if ((((e_) & k) == 0) ? ((va) < (vb)) : ((va) > (vb))) { ull t_ = (va); (va) = (vb); (vb) = t_; } }
  #define CSWAP_SHFL(vr, eo) { int e_ = wbase + (eo) + lane;                         \
      ull c_ = __shfl_xor((vr), j);                                                  \
      bool km_ = ((((e_) & k) == 0) == ((lane & j) == 0));                           \
      (vr) = km_ ? ((vr) > c_ ? (vr) : c_) : ((vr) < c_ ? (vr) : c_); }
  #define LOCALPHASES(jmax) {                                                        \
      for (int j = (jmax); j >= 1; j >>= 1) {                                        \
        if (j == 128)     { CSWAP_REG(v0, v2, 0);  CSWAP_REG(v1, v3, 64);  }         \
        else if (j == 64) { CSWAP_REG(v0, v1, 0);  CSWAP_REG(v2, v3, 128); }         \
        else { CSWAP_SHFL(v0, 0); CSWAP_SHFL(v1, 64); CSWAP_SHFL(v2, 128); CSWAP_SHFL(v3, 192); } } }

  LOADV;
  for (int k = 2; k <= 256; k <<= 1) { LOCALPHASES(k >> 1); }
  STOREV;
  __syncthreads();

  for (int k = 512; k <= NBOX; k <<= 1) {
    for (int j = k >> 1; j >= 256; j >>= 1) {
      for (int i = tid; i < NBOX; i += NTHR) {
        int l = i ^ j;
        if (l > i) {
          ull a = sm.skey[i], c = sm.skey[l];
          if (((i & k) == 0) ? (a < c) : (a > c)) { sm.skey[i] = c; sm.skey[l] = a; }
        }
      }
      __syncthreads();
    }
    LOADV;
    LOCALPHASES(128);
    STOREV;
    __syncthreads();
  }

  int* wsb = ws_sorted + (size_t)b * N;
  wsb[wbase       + lane] = (int)(0xFFFFFFFFu - (unsigned)v0);
  wsb[wbase +  64 + lane] = (int)(0xFFFFFFFFu - (unsigned)v1);
  wsb[wbase + 128 + lane] = (int)(0xFFFFFFFFu - (unsigned)v2);
  wsb[wbase + 192 + lane] = (int)(0xFFFFFFFFu - (unsigned)v3);
  int vc = (int)((v0 >> 32) != 0) + (int)((v1 >> 32) != 0)
         + (int)((v2 >> 32) != 0) + (int)((v3 >> 32) != 0);
  atomicAdd(&sm.vcount, vc);
  __syncthreads();
  if (tid == 0) ws_V[b] = sm.vcount;
}

// =================== kernel P: gather sorted clipped+offset boxes + areas ===================
__global__ __launch_bounds__(NTHR)
void prep_kernel(const float* __restrict__ boxes,
                 const int*   __restrict__ labels,
                 const int*   __restrict__ img_i,
                 const int*   __restrict__ ws_sorted,
                 float4* __restrict__ obox,
                 float*  __restrict__ area,
                 int N)
{
  const int b = blockIdx.y;
  const int i = blockIdx.x * NTHR + threadIdx.x;
  float fimg = getimg(img_i);
  float offs = fimg + 1.0f;
  int orig = ws_sorted[(size_t)b * N + i];
  float4 bb = ((const float4*)(boxes + (size_t)b * N * 4))[orig];
  float off = (float)labels[(size_t)b * N + orig] * offs;
  bb.x = clipf(bb.x, fimg) + off;
  bb.y = clipf(bb.y, fimg) + off;
  bb.z = clipf(bb.z, fimg) + off;
  bb.w = clipf(bb.w, fimg) + off;
  obox[(size_t)b * NBOX + i] = bb;
  area[(size_t)b * NBOX + i] = fmaxf(bb.z - bb.x, 0.0f) * fmaxf(bb.w - bb.y, 0.0f);
}

// =================== kernel M: suppression matrix CHUNK ===================
__global__ __launch_bounds__(256)
void supmat_chunk(const float4* __restrict__ obox,
                  const float*  __restrict__ area,
                  const float*  __restrict__ nms_th,
                  const int*    __restrict__ ws_V,
                  const int*    __restrict__ ws_done,
                  ull* __restrict__ supmat,
                  int c1_tiles, int wlo)
{
  __shared__ float4 cbox[CTW * 64];
  __shared__ float  carea[CTW * 64];
  __shared__ float4 rbox[64];
  __shared__ float  rarea[64];

  const int b   = blockIdx.y;
  if (ws_done[b]) return;
  const int rt  = blockIdx.x % c1_tiles;
  const int g   = blockIdx.x / c1_tiles;
  const int tid = threadIdx.x;
  const int V   = ws_V[b];
  const int JW  = (V + 63) >> 6;

  const int wlo_g = wlo + g * CTW;
  const int w0 = (wlo_g > rt) ? wlo_g : rt;
  const int w1 = (wlo_g + CTW < JW) ? wlo_g + CTW : JW;
  if (rt >= JW || w0 >= w1) return;

  double xt = (double)(*nms_th);
  float  th = (float)(1.0 / (1.0 + exp(-xt)));

  const float4* ob = obox + (size_t)b * NBOX;
  const float*  ar = area + (size_t)b * NBOX;

  const int e1 = (w1 - w0) * 64;
  for (int e = tid; e < e1; e += 256) {
    cbox[e]  = ob[w0 * 64 + e];
    carea[e] = ar[w0 * 64 + e];
  }
  if (tid < 64) {
    rbox[tid]  = ob[rt * 64 + tid];
    rarea[tid] = ar[rt * 64 + tid];
  }
  __syncthreads();

  const int wave  = tid >> 6;
  const int lane  = tid & 63;
  const int rbase = wave * 16;
  ull* sb = supmat + (size_t)b * NBOX * ROWW;

  for (int w = w0; w < w1; ++w) {
    const float4 bj = cbox[(w - w0) * 64 + lane];
    const float  aj = carea[(w - w0) * 64 + lane];
    const int    j  = w * 64 + lane;
    #pragma unroll 4
    for (int rr = 0; rr < 16; ++rr) {
      const int i = rt * 64 + rbase + rr;
      if (i >= V) break;
      const float4 bi = rbox[rbase + rr];
      const float  ai = rarea[rbase + rr];
      float xx1 = fmaxf(bi.x, bj.x);
      float yy1 = fmaxf(bi.y, bj.y);
      float xx2 = fminf(bi.z, bj.z);
      float yy2 = fminf(bi.w, bj.w);
      float inter = fmaxf(xx2 - xx1, 0.0f) * fmaxf(yy2 - yy1, 0.0f);
      float denom = ai + aj;           // ((areas[i]+areas[j]) - inter) + 1e-9, ref order
      denom = denom - inter;
      denom = denom + 1e-9f;
      float iou = inter / denom;
      ull word = __ballot((iou > th) && (j > i));
      if (lane == 0) sb[(size_t)i * ROWW + w] = word;
    }
  }
}

// =================== kernel R: greedy resolve CHUNK, transpose + ballot walk ===================
// State across chunks (in ws): done[b], total[b], kept[b][MAXDET].
template <int W>   // W = t1 - t0 words (16 or 32)
__global__ __launch_bounds__(256)
void resolve_chunk(const float* __restrict__ boxes,
                   const float* __restrict__ scores,
                   const int*   __restrict__ labels,
                   const int*   __restrict__ img_i,
                   float* __restrict__ out,
                   int B, int N,
                   const int* __restrict__ ws_sorted,
                   const int* __restrict__ ws_V,
                   const ull* __restrict__ supmat,
                   int* __restrict__ ws_done,
                   int* __restrict__ ws_total,
                   int* __restrict__ ws_kept,
                   int t0, int t1)
{
  __shared__ ull tbuf[2][64 * W];     // 16KB (W=16) / 32KB (W=32), double-buffered
  __shared__ ull comb[4][32];
  __shared__ ull kmask_sh[W];         // per-tile kept masks
  __shared__ int kept_sh[MAXDET];
  __shared__ int ctrl[3];             // [0]=total, [1]=hit-300 flag, [2]=ntiles

  const int b = blockIdx.x;
  if (ws_done[b]) return;
  const int tid  = threadIdx.x;
  const int wave = tid >> 6;
  const int lane = tid & 63;
  const int V    = ws_V[b];
  const int JW   = (V + 63) >> 6;
  const ull* smat = supmat + (size_t)b * NBOX * ROWW;
  int* kg = ws_kept + (size_t)b * MAXDET;

  const int total_in = (t0 == 0) ? 0 : ws_total[b];

  // ---- catch-up: OR of prior kept rows over this chunk's words (all 4 waves) ----
  if (t0 > 0) {
    ull acc = 0;
    for (int k = wave; k < total_in; k += 4) {
      int r = kg[k];
      if (lane < W) acc |= smat[(size_t)r * ROWW + t0 + lane];
    }
    if (lane < 32) comb[wave][lane] = (lane < W) ? acc : 0ull;
  }
  if (tid == 0) { ctrl[0] = total_in; ctrl[1] = 0; ctrl[2] = 0; }
  __syncthreads();

  // wave-0 alive registers: lane w (< W) owns global word t0+w
  ull alive = 0;
  if (wave == 0 && lane < W) {
    int lo = (t0 + lane) * 64;
    if (V > lo) { int n = V - lo; alive = (n >= 64) ? ~0ull : ((1ull << n) - 1ull); }
    if (t0 > 0) alive &= ~(comb[0][lane] | comb[1][lane] | comb[2][lane] | comb[3][lane]);
  }
  int total = total_in;
  const int tmax = (t1 < JW) ? t1 : JW;
  const int cw   = (lane < W) ? lane : 0;   // safe word-lane for LDS reads

  // stage first tile (rows 64 x words [t0,t1), swizzled)
  if (t0 < tmax) {
    const ull* src = smat + (size_t)t0 * 64 * ROWW + t0;
    #pragma unroll
    for (int c = 0; c < W / 4; ++c) {
      int e = tid + c * 256;
      int row = e / W, w = e % W;
      tbuf[0][row * W + (w ^ (row & (W - 1)))] = src[(size_t)row * ROWW + w];
    }
  }
  __syncthreads();

  for (int t = t0; t < tmax; ++t) {
    const int cur = (t - t0) & 1;
    ull r[W / 4];
    const bool pf = (t + 1 < tmax);
    if (pf) {                          // prefetch next tile into registers
      const ull* src = smat + (size_t)(t + 1) * 64 * ROWW + t0;
      #pragma unroll
      for (int c = 0; c < W / 4; ++c) {
        int e = tid + c * 256;
        int row = e / W, w = e % W;
        r[c] = src[(size_t)row * ROWW + w];
      }
    }
    if (wave == 0) {
      ull aw = __shfl(alive, t - t0);
      ull keptmask = 0;
      if (aw) {
        // lane holds row (t*64+lane) word t: boxes suppressed BY lane (bit m, m>lane)
        ull suprow = tbuf[cur][lane * W + ((t - t0) ^ (lane & (W - 1)))];
        // in-wave 64x64 bit transpose -> supbyT[lane] bit m = "lane suppressed by m"
        ull supbyT = 0;
        #pragma unroll
        for (int l = 0; l < 64; ++l) {
          ull bl = __ballot((suprow >> l) & 1ull);  // bit m = row m bit l = "l suppressed by m"
          if (lane == l) supbyT = bl;               // lane l's suppressed-by mask
        }
        ull rem = aw;
        bool done = false;
        while (rem) {
          int l = __builtin_ctzll(rem);
          rem &= rem - 1;
          keptmask |= (1ull << l);
          ++total;
          if (total == MAXDET) { done = true; break; }
          // bit m = "m suppressed by kept l" (bits only at m>l by construction)
          ull su = __ballot((supbyT >> l) & 1ull);
          rem &= ~su;
        }
        if (!done) {
          // apply kept rows to later words (4 accumulators -> pipelined ds_reads)
          ull a0 = 0, a1 = 0, a2 = 0, a3 = 0;
          ull km = keptmask;
          while (km) {
            int l = __builtin_ctzll(km); km &= km - 1;
            a0 |= tbuf[cur][l * W + (cw ^ (l & (W - 1)))];
            if (km) { l = __builtin_ctzll(km); km &= km - 1; a1 |= tbuf[cur][l * W + (cw ^ (l & (W - 1)))]; }
            if (km) { l = __builtin_ctzll(km); km &= km - 1; a2 |= tbuf[cur][l * W + (cw ^ (l & (W - 1)))]; }
            if (km) { l = __builtin_ctzll(km); km &= km - 1; a3 |= tbuf[cur][l * W + (cw ^ (l & (W - 1)))]; }
          }
          if (lane < W && (t0 + lane) > t) alive &= ~((a0 | a1) | (a2 | a3));
        } else if (lane == 0) {
          ctrl[1] = 1;
        }
      }
      if (lane == 0) { kmask_sh[t - t0] = keptmask; ctrl[0] = total; ctrl[2] = t - t0 + 1; }
    }
    __syncthreads();
    if (ctrl[1]) break;                // uniform early exit at 300 kept
    if (pf) {
      #pragma unroll
      for (int c = 0; c < W / 4; ++c) {
        int e = tid + c * 256;
        int row = e / W, w = e % W;
        tbuf[cur ^ 1][row * W + (w ^ (row & (W - 1)))] = r[c];
      }
    }
    __syncthreads();
  }

  // ---- expand kept masks -> kept_sh (wave 0: lane per tile, prefix scan) ----
  const int ntiles = ctrl[2];
  if (wave == 0) {
    ull km = (lane < ntiles) ? kmask_sh[lane] : 0ull;
    int pc = __popcll(km);
    int incl = pc;
    #pragma unroll
    for (int s = 1; s < 64; s <<= 1) {
      int v = __shfl_up(incl, s);
      if (lane >= s) incl += v;
    }
    int base = total_in + incl - pc;
    while (km) {
      int l = __builtin_ctzll(km);
      km &= km - 1;
      kept_sh[base++] = (t0 + lane) * 64 + l;
    }
  }
  __syncthreads();

  const int K = ctrl[0];
  // persist new kept entries for later chunks
  for (int rI = total_in + tid; rI < K; rI += 256) kg[rI] = kept_sh[rI];

  const bool finished = (ctrl[1] != 0) || (t1 >= JW);
  if (!finished) {
    if (tid == 0) ws_total[b] = K;
    return;
  }
  if (tid == 0) ws_done[b] = 1;

  // ---- outputs ----
  float fimg = getimg(img_i);
  const float* bx = boxes  + (size_t)b * N * 4;
  const float* sc = scores + (size_t)b * N;
  const int*   lb = labels + (size_t)b * N;
  const int*   so = ws_sorted + (size_t)b * N;

  float4* obx = (float4*)out;
  float*  osc = out + (size_t)B * MAXDET * 4;
  float*  olb = osc + (size_t)B * MAXDET;
  float*  ovl = olb + (size_t)B * MAXDET;
  for (int rI = tid; rI < MAXDET; rI += 256) {
    size_t slot = (size_t)b * MAXDET + rI;
    if (rI < K) {
      int i    = (rI < total_in) ? kg[rI] : kept_sh[rI];
      int orig = so[i];
      float4 bb = ((const float4*)bx)[orig];
      bb.x = clipf(bb.x, fimg);
      bb.y = clipf(bb.y, fimg);
      bb.z = clipf(bb.z, fimg);
      bb.w = clipf(bb.w, fimg);
      obx[slot] = bb;
      osc[slot] = sc[orig];
      olb[slot] = (float)lb[orig];
      ovl[slot] = 1.0f;
    } else {
      obx[slot] = make_float4(0.f, 0.f, 0.f, 0.f);
      osc[slot] = 0.0f;
      olb[slot] = 0.0f;
      ovl[slot] = 0.0f;
    }
  }
}

// =================== fallback kernel (round-2 path, used if ws too small) ===================
struct SMB {
  float4       obox[CAP];
  unsigned int keepw[NWORDS];
  int          kept_pos[MAXDET];
  int          scal[4];
};

__global__ __launch_bounds__(NTHR)
void nms_kernel(const float* __restrict__ boxes,
                const float* __restrict__ scores,
                const int*   __restrict__ labels,
                const float* __restrict__ nms_th,
                const float* __restrict__ cls_w,
                const int*   __restrict__ img_i,
                float* __restrict__ out,
                int B, int N,
                const int* __restrict__ ws_sorted,
                const int* __restrict__ ws_V,
                float4* __restrict__ ws_ovf)
{
  __shared__ SMB sm;
  const int b    = blockIdx.x;
  const int tid  = threadIdx.x;

  const float* bx = boxes  + (size_t)b * N * 4;
  const float* sc = scores + (size_t)b * N;
  const int*   lb = labels + (size_t)b * N;
  const int*   so = ws_sorted + (size_t)b * N;

  float fimg = getimg(img_i);
  float off_scale = fimg + 1.0f;
  double xt = (double)(*nms_th);
  float  th = (float)(1.0 / (1.0 + exp(-xt)));

  const int V = ws_V[b];
  if (tid < 4) sm.scal[tid] = 0;

  for (int m = 0; m < 4; ++m) {
    int i = tid + m * NTHR;
    int orig = so[i];
    float4 bb = ((const float4*)bx)[orig];
    float off = (float)lb[orig] * off_scale;
    bb.x = clipf(bb.x, fimg) + off;
    bb.y = clipf(bb.y, fimg) + off;
    bb.z = clipf(bb.z, fimg) + off;
    bb.w = clipf(bb.w, fimg) + off;
    if (i < CAP) sm.obox[i] = bb;
    else         ws_ovf[(size_t)b * (NBOX - CAP) + (i - CAP)] = bb;
  }
  for (int w = tid; w < NWORDS; w += NTHR) {
    int lo = w * 32;
    unsigned val;
    if      (V >= lo + 32) val = 0xFFFFFFFFu;
    else if (V <= lo)      val = 0u;
    else                   val = (1u << (V - lo)) - 1u;
    sm.keepw[w] = val;
  }
  __syncthreads();

  const int nt = (V + 63) >> 6;
  int TR = 0;
  for (int t = 0; t < nt; ++t) {
    if (tid < 64) {
      int i0 = t * 64;
      int me = i0 + tid;
      float4 bb = (me < CAP) ? sm.obox[me]
                             : ws_ovf[(size_t)b * (NBOX - CAP) + (me - CAP)];
      float arJ = fmaxf(bb.z - bb.x, 0.0f) * fmaxf(bb.w - bb.y, 0.0f);
      ull supby = 0;
      for (int l = 0; l < 64; ++l) {
        int i = i0 + l;
        float4 bi = (i < CAP) ? sm.obox[i]
                              : ws_ovf[(size_t)b * (NBOX - CAP) + (i - CAP)];
        float ai = fmaxf(bi.z - bi.x, 0.0f) * fmaxf(bi.w - bi.y, 0.0f);
        float xx1 = fmaxf(bi.x, bb.x);
        float yy1 = fmaxf(bi.y, bb.y);
        float xx2 = fminf(bi.z, bb.z);
        float yy2 = fminf(bi.w, bb.w);
        float inter = fmaxf(xx2 - xx1, 0.0f) * fmaxf(yy2 - yy1, 0.0f);
        float denom = ai + arJ;
        denom = denom - inter;
        denom = denom + 1e-9f;
        float iou = inter / denom;
        if (iou > th) supby |= (1ull << l);
      }
      ull alive = ((ull)sm.keepw[2 * t + 1] << 32) | sm.keepw[2 * t];
      ull rem = alive;
      while (rem) {
        int l = __builtin_ctzll(rem);
        rem &= rem - 1;
        ull sup = __ballot((supby >> l) & 1ull);
        sup &= ((~1ull) << l);
        sup &= alive;
        alive &= ~sup;
        rem   &= ~sup;
      }
      if (tid == 0) {
        sm.keepw[2 * t]     = (unsigned)alive;
        sm.keepw[2 * t + 1] = (unsigned)(alive >> 32);
        atomicAdd(&sm.scal[1], __builtin_popcountll(alive));
      }
    }
    __syncthreads();
    TR = t + 1;
    if (sm.scal[1] >= MAXDET) break;

    int jstart = (t + 1) * 64;
    if (jstart < V) {
      ull alive = ((ull)sm.keepw[2 * t + 1] << 32) | sm.keepw[2 * t];
      if (alive) {
        for (int j = jstart + tid; j < V; j += NTHR) {
          unsigned wj = sm.keepw[j >> 5];
          if (!((wj >> (j & 31)) & 1u)) continue;
          float4 bj = (j < CAP) ? sm.obox[j]
                                : ws_ovf[(size_t)b * (NBOX - CAP) + (j - CAP)];
          float aj = fmaxf(bj.z - bj.x, 0.0f) * fmaxf(bj.w - bj.y, 0.0f);
          ull rem = alive;
          bool suppressed = false;
          while (rem) {
            int l = __builtin_ctzll(rem);
            rem &= rem - 1;
            int i = t * 64 + l;
            float4 bi = (i < CAP) ? sm.obox[i]
                                  : ws_ovf[(size_t)b * (NBOX - CAP) + (i - CAP)];
            float ai = fmaxf(bi.z - bi.x, 0.0f) * fmaxf(bi.w - bi.y, 0.0f);
            float xx1 = fmaxf(bi.x, bj.x);
            float yy1 = fmaxf(bi.y, bj.y);
            float xx2 = fminf(bi.z, bj.z);
            float yy2 = fminf(bi.w, bj.w);
            float inter = fmaxf(xx2 - xx1, 0.0f) * fmaxf(yy2 - yy1, 0.0f);
            float denom = ai + aj;
            denom = denom - inter;
            denom = denom + 1e-9f;
            float iou = inter / denom;
            if (iou > th) { suppressed = true; break; }
          }
          if (suppressed) atomicAnd(&sm.keepw[j >> 5], ~(1u << (j & 31)));
        }
      }
    }
    __syncthreads();
  }

  if (tid < NWORDS && tid >= TR * 2) sm.keepw[tid] = 0;
  __syncthreads();
  if (tid == 0) {
    int r = 0;
    for (int w = 0; w < NWORDS && r < MAXDET; ++w) {
      unsigned bits = sm.keepw[w];
      while (bits && r < MAXDET) {
        int l = __builtin_ctz(bits);
        bits &= bits - 1;
        sm.kept_pos[r++] = w * 32 + l;
      }
    }
    sm.scal[3] = r;
  }
  __syncthreads();
  const int K = sm.scal[3];

  float4* obx = (float4*)out;
  float*  osc = out + (size_t)B * MAXDET * 4;
  float*  olb = osc + (size_t)B * MAXDET;
  float*  ovl = olb + (size_t)B * MAXDET;
  for (int r = tid; r < MAXDET; r += NTHR) {
    size_t slot = (size_t)b * MAXDET + r;
    if (r < K) {
      int i    = sm.kept_pos[r];
      int orig = so[i];
      float4 bb = ((const float4*)bx)[orig];
      bb.x = clipf(bb.x, fimg);
      bb.y = clipf(bb.y, fimg);
      bb.z = clipf(bb.z, fimg);
      bb.w = clipf(bb.w, fimg);
      obx[slot] = bb;
      osc[slot] = sc[orig];
      olb[slot] = (float)lb[orig];
      ovl[slot] = 1.0f;
    } else {
      obx[slot] = make_float4(0.f, 0.f, 0.f, 0.f);
      osc[slot] = 0.0f;
      olb[slot] = 0.0f;
      ovl[slot] = 0.0f;
    }
  }
}

extern "C" void kernel_launch(void* const* d_in, const int* in_sizes, int n_in,
                              void* d_out, int out_size, void* d_ws, size_t ws_size,
                              hipStream_t stream) {
  const float* boxes      = (const float*)d_in[0];
  const float* scores     = (const float*)d_in[1];
  const int*   labels     = (const int*)d_in[2];
  const float* nms_thresh = (const float*)d_in[3];
  const float* cls_w      = (const float*)d_in[4];
  const int*   img_sz     = (const int*)d_in[5];

  int B = out_size / (MAXDET * 7);
  int N = in_sizes[1] / B;               // 4096

  // ws layout
  size_t sz_sorted = (size_t)B * N * 4;
  size_t off_V     = sz_sorted;
  size_t off_obox  = sz_sorted + 1024;
  size_t sz_obox   = (size_t)B * NBOX * 16;
  size_t off_area  = off_obox + sz_obox;
  size_t sz_area   = (size_t)B * NBOX * 4;
  size_t off_done  = (off_area + sz_area + 255) & ~(size_t)255;
  size_t off_total = off_done + (size_t)B * 4;
  size_t off_kept  = off_total + (size_t)B * 4;
  size_t off_sup   = (off_kept + (size_t)B * MAXDET * 4 + 255) & ~(size_t)255;
  size_t sz_sup    = (size_t)B * NBOX * ROWW * 8;   // 32 MiB at B=16
  size_t need_fast = off_sup + sz_sup;

  int* ws_sorted = (int*)d_ws;
  int* ws_V      = (int*)((char*)d_ws + off_V);
  int* ws_done   = (int*)((char*)d_ws + off_done);

  sort_kernel<<<dim3(B), dim3(NTHR), 0, stream>>>(scores, labels, cls_w,
                                                  ws_sorted, ws_V, ws_done, N);

  if (ws_size >= need_fast && N == NBOX) {
    float4* obox     = (float4*)((char*)d_ws + off_obox);
    float*  area     = (float*)((char*)d_ws + off_area);
    int*    ws_total = (int*)((char*)d_ws + off_total);
    int*    ws_kept  = (int*)((char*)d_ws + off_kept);
    ull*    supmat   = (ull*)((char*)d_ws + off_sup);

    prep_kernel<<<dim3(N / NTHR, B), dim3(NTHR), 0, stream>>>(
        boxes, labels, img_sz, ws_sorted, obox, area, N);

    // chunk 0: tiles [0,16)
    supmat_chunk<<<dim3(16, B), dim3(256), 0, stream>>>(
        obox, area, nms_thresh, ws_V, ws_done, supmat, 16, 0);
    resolve_chunk<16><<<dim3(B), dim3(256), 0, stream>>>(
        boxes, scores, labels, img_sz, (float*)d_out, B, N,
        ws_sorted, ws_V, supmat, ws_done, ws_total, ws_kept, 0, 16);

    // chunk 1: tiles [16,32)
    supmat_chunk<<<dim3(32, B), dim3(256), 0, stream>>>(
        obox, area, nms_thresh, ws_V, ws_done, supmat, 32, 16);
    resolve_chunk<16><<<dim3(B), dim3(256), 0, stream>>>(
        boxes, scores, labels, img_sz, (float*)d_out, B, N,
        ws_sorted, ws_V, supmat, ws_done, ws_total, ws_kept, 16, 32);

    // chunk 2: tiles [32,64)
    supmat_chunk<<<dim3(128, B), dim3(256), 0, stream>>>(
        obox, area, nms_thresh, ws_V, ws_done, supmat, 64, 32);
    resolve_chunk<32><<<dim3(B), dim3(256), 0, stream>>>(
        boxes, scores, labels, img_sz, (float*)d_out, B, N,
        ws_sorted, ws_V, supmat, ws_done, ws_total, ws_kept, 32, 64);
  } else {
    float4* ws_ovf = (float4*)((char*)d_ws + sz_sorted + 1024 + sz_obox + sz_area);
    nms_kernel<<<dim3(B), dim3(NTHR), 0, stream>>>(boxes, scores, labels,
                                                   nms_thresh, cls_w, img_sz,
                                                   (float*)d_out, B, N,
                                                   ws_sorted, ws_V, ws_ovf);
  }
}